// Round 1
// baseline (7990.014 us; speedup 1.0000x reference)
//
#include <hip/hip_runtime.h>
#include <math.h>

// Problem constants (fixed by the reference)
constexpr int B_  = 2;
constexpr int C_  = 96;     // DIM
constexpr int HW_ = 64;     // H == W
constexpr int L_  = 4096;   // H*W
constexpr int Di_ = 192;    // D_INNER
constexpr int N_  = 16;     // D_STATE
constexpr int R_  = 6;      // DT_RANK
constexpr int K_  = 4;      // directions

__device__ __forceinline__ float siluf(float x){ return x / (1.0f + __expf(-x)); }
__device__ __forceinline__ float softplusf(float x){ return x > 15.0f ? x : log1pf(__expf(x)); }
__device__ __forceinline__ float wave_sum(float v){
  #pragma unroll
  for (int off = 32; off > 0; off >>= 1) v += __shfl_xor(v, off, 64);
  return v;
}
// direction index maps: scan position l -> row-major spatial index
__device__ __forceinline__ int dir_idx(int k, int l){
  if (k == 0) return l;
  if (k == 1) return ((l & 63) << 6) | (l >> 6);
  if (k == 2) return (L_ - 1) - l;
  int lm = (L_ - 1) - l; return ((lm & 63) << 6) | (lm >> 6);
}

// ---------- layout shufflers ----------
__global__ void k_nchw2nhwc(const float* __restrict__ x, float* __restrict__ xf){
  long i = (long)blockIdx.x * 256 + threadIdx.x;      // over (b,l,c), c fast
  int c = (int)(i % 96); long p = i / 96; int b = (int)(p >> 12); int l = (int)(p & 4095);
  xf[i] = x[((long)b * 96 + c) * L_ + l];
}
__global__ void k_nhwc2nchw(const float* __restrict__ xf, float* __restrict__ out){
  long i = (long)blockIdx.x * 256 + threadIdx.x;      // over (b,c,l), l fast
  int l = (int)(i & 4095); long q = i >> 12; int c = (int)(q % 96); int b = (int)(q / 96);
  out[i] = xf[((long)b * L_ + l) * 96 + c];
}
__global__ void k_transpose(const float* __restrict__ w, float* __restrict__ wt, int rows, int cols){
  int t = blockIdx.x * 256 + threadIdx.x;
  if (t < rows * cols){ int r = t / cols, c = t % cols; wt[(long)c * rows + r] = w[t]; }
}

// ---------- layernorm over 96 channels (wave per pixel) ----------
__global__ void k_ln96(const float* __restrict__ in, float* __restrict__ out,
                       const float* __restrict__ g, const float* __restrict__ bb){
  int wave = threadIdx.x >> 6, lane = threadIdx.x & 63;
  long p = (long)blockIdx.x * 4 + wave;
  const float* row = in + p * 96;
  float v0 = row[lane];
  float v1 = (lane < 32) ? row[64 + lane] : 0.0f;
  float s  = wave_sum(v0 + v1);
  float sq = wave_sum(v0 * v0 + v1 * v1);
  float mean = s * (1.0f / 96.0f);
  float var  = sq * (1.0f / 96.0f) - mean * mean;
  float rs = rsqrtf(var + 1e-5f);
  out[p * 96 + lane] = (v0 - mean) * rs * g[lane] + bb[lane];
  if (lane < 32) out[p * 96 + 64 + lane] = (v1 - mean) * rs * g[64 + lane] + bb[64 + lane];
}

// ---------- in_proj: (B*L,96) x Wt(96,384) -> xz (B*L,384) ----------
__global__ void k_inproj(const float* __restrict__ h, const float* __restrict__ wt,
                         float* __restrict__ xz){
  __shared__ float hb[96];
  long p = blockIdx.x;
  int e = threadIdx.x;                 // 0..383
  if (e < 96) hb[e] = h[p * 96 + e];
  __syncthreads();
  float acc = 0.f;
  #pragma unroll 8
  for (int c = 0; c < 96; c++) acc += hb[c] * wt[(long)c * 384 + e];
  xz[p * 384 + e] = acc;
}

// ---------- depthwise 3x3 conv + bias + silu: xz(:, :192) -> u (B,Di,L) planar ----------
__global__ void k_dwconv(const float* __restrict__ xz, const float* __restrict__ cw,
                         const float* __restrict__ cb, float* __restrict__ u){
  int l = blockIdx.x * 64 + threadIdx.x;
  int d = blockIdx.y, b = blockIdx.z;
  int hh = l >> 6, ww = l & 63;
  float acc = cb[d];
  #pragma unroll
  for (int dh = -1; dh <= 1; dh++){
    int h2 = hh + dh; if (h2 < 0 || h2 >= 64) continue;
    #pragma unroll
    for (int dw = -1; dw <= 1; dw++){
      int w2 = ww + dw; if (w2 < 0 || w2 >= 64) continue;
      acc += xz[((long)b * L_ + h2 * 64 + w2) * 384 + d] * cw[d * 9 + (dh + 1) * 3 + (dw + 1)];
    }
  }
  u[((long)b * Di_ + d) * L_ + l] = siluf(acc);
}

// ---------- x_dbl[b,k,c,l] = sum_d u[b,d,idx_k(l)] * xw[k,c,d]  (c = 0..37) ----------
__global__ void k_xdbl(const float* __restrict__ u, const float* __restrict__ xw,
                       float* __restrict__ xd){
  int l = blockIdx.x * 256 + threadIdx.x;
  int bk = blockIdx.y; int b = bk >> 2, k = bk & 3;
  int idx = dir_idx(k, l);
  float acc[38];
  #pragma unroll
  for (int c = 0; c < 38; c++) acc[c] = 0.f;
  const float* ub = u + (long)b * Di_ * L_;
  const float* wb = xw + (long)k * 38 * Di_;
  for (int d = 0; d < Di_; d++){
    float uv = ub[(long)d * L_ + idx];
    #pragma unroll
    for (int c = 0; c < 38; c++) acc[c] += uv * wb[c * Di_ + d];
  }
  float* o = xd + (long)bk * 38 * L_ + l;
  #pragma unroll
  for (int c = 0; c < 38; c++) o[(long)c * L_] = acc[c];
}

// ---------- selective scan: wave = 4 channels x 16 states; atomic-accumulate y ----------
__global__ void __launch_bounds__(64) k_scan(
    const float* __restrict__ xd, const float* __restrict__ u,
    const float* __restrict__ Alog, const float* __restrict__ dtw,
    const float* __restrict__ dtb, const float* __restrict__ Dsk,
    float* __restrict__ ycl){
  int bid = bid = blockIdx.x;
  int b = bid / (K_ * 48); int rem = bid % (K_ * 48);
  int k = rem / 48; int dch = rem % 48;
  int lane = threadIdx.x;
  int dsub = lane >> 4, n = lane & 15;
  int d = dch * 4 + dsub;
  int kd = k * Di_ + d;
  float Av = -__expf(Alog[(long)kd * 16 + n]);
  float w0 = dtw[kd*6+0], w1 = dtw[kd*6+1], w2 = dtw[kd*6+2];
  float w3 = dtw[kd*6+3], w4 = dtw[kd*6+4], w5 = dtw[kd*6+5];
  float bias = dtb[kd];
  float Dv = Dsk[kd];
  const float* xb = xd + (long)(b * K_ + k) * 38 * L_;
  const float* ub = u + (long)(b * Di_ + d) * L_;
  float* yb = ycl + (long)b * L_ * Di_;
  float h = 0.f;
  for (int l = 0; l < L_; l++){
    int idx = dir_idx(k, l);
    float r0 = xb[l], r1 = xb[L_ + l], r2 = xb[2*L_ + l];
    float r3 = xb[3*L_ + l], r4 = xb[4*L_ + l], r5 = xb[5*L_ + l];
    float draw = bias + w0*r0 + w1*r1 + w2*r2 + w3*r3 + w4*r4 + w5*r5;
    float delta = softplusf(draw);
    float uv = ub[idx];
    float bn = xb[(long)(6  + n) * L_ + l];
    float cn = xb[(long)(22 + n) * L_ + l];
    float dA = __expf(delta * Av);
    h = dA * h + (delta * uv) * bn;
    float pr = h * cn;
    pr += __shfl_xor(pr, 1, 16);
    pr += __shfl_xor(pr, 2, 16);
    pr += __shfl_xor(pr, 4, 16);
    pr += __shfl_xor(pr, 8, 16);
    if (n == 0) atomicAdd(&yb[(long)idx * Di_ + d], pr + Dv * uv);
  }
}

// ---------- out_norm (LN over 192) * silu(z), in-place on ycl ----------
__global__ void k_outnorm(float* __restrict__ y, const float* __restrict__ xz,
                          const float* __restrict__ g, const float* __restrict__ bb){
  int wave = threadIdx.x >> 6, lane = threadIdx.x & 63;
  long p = (long)blockIdx.x * 4 + wave;
  float* row = y + p * 192;
  float v0 = row[lane], v1 = row[lane + 64], v2 = row[lane + 128];
  float s  = wave_sum(v0 + v1 + v2);
  float sq = wave_sum(v0*v0 + v1*v1 + v2*v2);
  float mean = s * (1.0f / 192.0f);
  float var  = sq * (1.0f / 192.0f) - mean * mean;
  float rs = rsqrtf(var + 1e-5f);
  const float* zr = xz + p * 384 + 192;
  row[lane]       = ((v0 - mean) * rs * g[lane]       + bb[lane])       * siluf(zr[lane]);
  row[lane + 64]  = ((v1 - mean) * rs * g[lane + 64]  + bb[lane + 64])  * siluf(zr[lane + 64]);
  row[lane + 128] = ((v2 - mean) * rs * g[lane + 128] + bb[lane + 128]) * siluf(zr[lane + 128]);
}

// ---------- out_proj (192->96) + skip1: xc = xf*skip1 + y @ Wt ----------
__global__ void k_outproj(const float* __restrict__ y, const float* __restrict__ wt,
                          const float* __restrict__ xf, const float* __restrict__ skip,
                          float* __restrict__ xc){
  __shared__ float yb[384];
  long p0 = (long)blockIdx.x * 2;
  int t = threadIdx.x;                  // 0..191
  yb[t]       = y[p0 * 192 + t];
  yb[t + 192] = y[(p0 + 1) * 192 + t];
  __syncthreads();
  int pp = t / 96, c = t % 96;
  long p = p0 + pp;
  float acc = 0.f;
  #pragma unroll 8
  for (int d = 0; d < 192; d++) acc += yb[pp * 192 + d] * wt[d * 96 + c];
  xc[p * 96 + c] = xf[p * 96 + c] * skip[c] + acc;
}

// ---------- CAB conv1 3x3 96->32 + exact gelu ----------
__global__ void k_cab1(const float* __restrict__ in, const float* __restrict__ w1,
                       const float* __restrict__ b1, float* __restrict__ t1){
  int t = threadIdx.x;
  int o = t & 31, pl = t >> 5;
  long pix = (long)blockIdx.x * 8 + pl;
  int b = (int)(pix >> 12); int l = (int)(pix & 4095);
  int hh = l >> 6, ww = l & 63;
  float acc = b1[o];
  for (int dh = -1; dh <= 1; dh++){
    int h2 = hh + dh; if (h2 < 0 || h2 >= 64) continue;
    for (int dw = -1; dw <= 1; dw++){
      int w2 = ww + dw; if (w2 < 0 || w2 >= 64) continue;
      const float* ir = in + ((long)b * L_ + h2 * 64 + w2) * 96;
      const float* wr = w1 + (long)o * 96 * 9 + (dh + 1) * 3 + (dw + 1);
      #pragma unroll 8
      for (int ci = 0; ci < 96; ci++) acc += ir[ci] * wr[ci * 9];
    }
  }
  t1[pix * 32 + o] = 0.5f * acc * (1.0f + erff(acc * 0.70710678118654752f));
}

// ---------- CAB conv2 3x3 32->96 (no activation) ----------
__global__ void k_cab2(const float* __restrict__ t1, const float* __restrict__ w2,
                       const float* __restrict__ b2, float* __restrict__ yc){
  int t = threadIdx.x;
  int o = t % 96, pl = t / 96;
  long pix = (long)blockIdx.x * 2 + pl;
  int b = (int)(pix >> 12); int l = (int)(pix & 4095);
  int hh = l >> 6, ww = l & 63;
  float acc = b2[o];
  for (int dh = -1; dh <= 1; dh++){
    int h2 = hh + dh; if (h2 < 0 || h2 >= 64) continue;
    for (int dw = -1; dw <= 1; dw++){
      int w2i = ww + dw; if (w2i < 0 || w2i >= 64) continue;
      const float* ir = t1 + ((long)b * L_ + h2 * 64 + w2i) * 32;
      const float* wr = w2 + (long)o * 32 * 9 + (dh + 1) * 3 + (dw + 1);
      #pragma unroll
      for (int ci = 0; ci < 32; ci++) acc += ir[ci] * wr[ci * 9];
    }
  }
  yc[pix * 96 + o] = acc;
}

// ---------- channel-attention: partial mean, then squeeze-excite ----------
__global__ void k_meanpart(const float* __restrict__ yc, float* __restrict__ part){
  int b = blockIdx.x >> 5, ch = blockIdx.x & 31;
  int o = threadIdx.x;
  float acc = 0.f;
  const float* base = yc + ((long)b * L_ + ch * 128) * 96 + o;
  for (int r = 0; r < 128; r++) acc += base[(long)r * 96];
  part[(long)blockIdx.x * 96 + o] = acc;
}
__global__ void k_attn(const float* __restrict__ part, const float* __restrict__ dw,
                       const float* __restrict__ db, const float* __restrict__ uw,
                       const float* __restrict__ ub, float* __restrict__ a){
  __shared__ float pv[96];
  __shared__ float tv[3];
  int b = blockIdx.x, o = threadIdx.x;
  float acc = 0.f;
  for (int ch = 0; ch < 32; ch++) acc += part[(long)(b * 32 + ch) * 96 + o];
  pv[o] = acc * (1.0f / 4096.0f);
  __syncthreads();
  if (o < 3){
    float t = db[o];
    for (int i2 = 0; i2 < 96; i2++) t += pv[i2] * dw[o * 96 + i2];
    tv[o] = t > 0.f ? t : 0.f;
  }
  __syncthreads();
  float av = ub[o] + tv[0] * uw[o * 3 + 0] + tv[1] * uw[o * 3 + 1] + tv[2] * uw[o * 3 + 2];
  a[b * 96 + o] = 1.0f / (1.0f + __expf(-av));
}

// ---------- final mix: xf = xc*skip2 + ycab*a ----------
__global__ void k_mix(const float* __restrict__ xc, const float* __restrict__ yc,
                      const float* __restrict__ a, const float* __restrict__ skip2,
                      float* __restrict__ xf){
  long i = (long)blockIdx.x * 256 + threadIdx.x;
  int c = (int)(i % 96); long p = i / 96; int b = (int)(p >> 12);
  xf[i] = xc[i] * skip2[c] + yc[i] * a[b * 96 + c];
}

extern "C" void kernel_launch(void* const* d_in, const int* in_sizes, int n_in,
                              void* d_out, int out_size, void* d_ws, size_t ws_size,
                              hipStream_t stream){
  const float* x          = (const float*)d_in[0];
  const float* ln1_g      = (const float*)d_in[1];
  const float* ln1_b      = (const float*)d_in[2];
  const float* in_proj_w  = (const float*)d_in[3];
  const float* conv_w     = (const float*)d_in[4];
  const float* conv_b     = (const float*)d_in[5];
  const float* x_proj_w   = (const float*)d_in[6];
  const float* dt_proj_w  = (const float*)d_in[7];
  const float* dt_proj_b  = (const float*)d_in[8];
  const float* A_logs     = (const float*)d_in[9];
  const float* Ds         = (const float*)d_in[10];
  const float* out_norm_g = (const float*)d_in[11];
  const float* out_norm_b = (const float*)d_in[12];
  const float* out_proj_w = (const float*)d_in[13];
  const float* skip1      = (const float*)d_in[14];
  const float* ln2_g      = (const float*)d_in[15];
  const float* ln2_b      = (const float*)d_in[16];
  const float* cab1_w     = (const float*)d_in[17];
  const float* cab1_b     = (const float*)d_in[18];
  const float* cab2_w     = (const float*)d_in[19];
  const float* cab2_b     = (const float*)d_in[20];
  const float* ca_dw      = (const float*)d_in[21];
  const float* ca_db      = (const float*)d_in[22];
  const float* ca_uw      = (const float*)d_in[23];
  const float* ca_ub      = (const float*)d_in[24];
  const float* skip2      = (const float*)d_in[25];

  float* W = (float*)d_ws;
  float* xf   = W + 0;         // 786432   (B,L,C)  current features
  float* hb   = W + 786432;    // 786432   ln output (reused ln1/ln2)
  float* xz   = W + 1572864;   // 3145728  (B,L,384) in_proj out (xp|z)
  float* u    = W + 4718592;   // 1572864  (B,Di,L) conv+silu
  float* xd   = W + 6291456;   // 1245184  (B,K,38,L)
  float* ycl  = W + 7536640;   // 1572864  (B,L,Di) scan accumulate / gated
  float* xc   = W + 9109504;   // 786432   (B,L,C)
  float* t1   = W + 9895936;   // 262144   (B,L,32)
  float* ycab = W + 10158080;  // 786432   (B,L,96)
  float* part = W + 10944512;  // 6144
  float* abuf = W + 10950656;  // 192
  float* wti  = W + 10950848;  // 36864    in_proj_w transposed (96,384)
  float* wto  = W + 10987712;  // 18432    out_proj_w transposed (192,96)

  k_nchw2nhwc<<<dim3(3072), dim3(256), 0, stream>>>(x, xf);

  for (int i = 0; i < 2; i++){
    const float* ipw  = in_proj_w  + (long)i * 384 * 96;
    const float* opw  = out_proj_w + (long)i * 96 * 192;
    const float* cw   = conv_w     + (long)i * 192 * 9;
    const float* cb   = conv_b     + (long)i * 192;
    const float* xpw  = x_proj_w   + (long)i * 4 * 38 * 192;
    const float* dtw  = dt_proj_w  + (long)i * 4 * 192 * 6;
    const float* dtbp = dt_proj_b  + (long)i * 4 * 192;
    const float* alog = A_logs     + (long)i * 768 * 16;
    const float* dsp  = Ds         + (long)i * 768;

    k_transpose<<<dim3(144), dim3(256), 0, stream>>>(ipw, wti, 384, 96);
    k_transpose<<<dim3(72),  dim3(256), 0, stream>>>(opw, wto, 96, 192);

    k_ln96<<<dim3(2048), dim3(256), 0, stream>>>(xf, hb, ln1_g + i*96, ln1_b + i*96);
    k_inproj<<<dim3(8192), dim3(384), 0, stream>>>(hb, wti, xz);
    k_dwconv<<<dim3(64, 192, 2), dim3(64), 0, stream>>>(xz, cw, cb, u);
    k_xdbl<<<dim3(16, 8), dim3(256), 0, stream>>>(u, xpw, xd);

    hipMemsetAsync(ycl, 0, (size_t)1572864 * sizeof(float), stream);
    k_scan<<<dim3(384), dim3(64), 0, stream>>>(xd, u, alog, dtw, dtbp, dsp, ycl);

    k_outnorm<<<dim3(2048), dim3(256), 0, stream>>>(ycl, xz, out_norm_g + i*192, out_norm_b + i*192);
    k_outproj<<<dim3(4096), dim3(192), 0, stream>>>(ycl, wto, xf, skip1 + i*96, xc);

    k_ln96<<<dim3(2048), dim3(256), 0, stream>>>(xc, hb, ln2_g + i*96, ln2_b + i*96);
    k_cab1<<<dim3(1024), dim3(256), 0, stream>>>(hb, cab1_w + (long)i*32*96*9, cab1_b + i*32, t1);
    k_cab2<<<dim3(4096), dim3(192), 0, stream>>>(t1, cab2_w + (long)i*96*32*9, cab2_b + i*96, ycab);
    k_meanpart<<<dim3(64), dim3(96), 0, stream>>>(ycab, part);
    k_attn<<<dim3(2), dim3(96), 0, stream>>>(part, ca_dw + i*288, ca_db + i*3,
                                             ca_uw + i*288, ca_ub + i*96, abuf);
    k_mix<<<dim3(3072), dim3(256), 0, stream>>>(xc, ycab, abuf, skip2 + i*96, xf);
  }

  k_nhwc2nchw<<<dim3(3072), dim3(256), 0, stream>>>(xf, (float*)d_out);
}

// Round 2
// 3995.560 us; speedup vs baseline: 1.9997x; 1.9997x over previous
//
#include <hip/hip_runtime.h>
#include <math.h>

// Problem constants (fixed by the reference)
constexpr int B_  = 2;
constexpr int C_  = 96;     // DIM
constexpr int L_  = 4096;   // H*W
constexpr int Di_ = 192;    // D_INNER
constexpr int N_  = 16;     // D_STATE
constexpr int K_  = 4;      // directions
constexpr int CH_ = 32;     // scan chunks
constexpr int CL_ = 128;    // chunk length (CH_*CL_ == L_)
constexpr int TL_ = 24576;  // total state lanes = B*K*Di*N

__device__ __forceinline__ float siluf(float x){ return x / (1.0f + __expf(-x)); }
__device__ __forceinline__ float softplusf(float x){ return x > 15.0f ? x : log1pf(__expf(x)); }
__device__ __forceinline__ float wave_sum(float v){
  #pragma unroll
  for (int off = 32; off > 0; off >>= 1) v += __shfl_xor(v, off, 64);
  return v;
}
// direction index maps: scan position l -> row-major spatial index
__device__ __forceinline__ int dir_idx(int k, int l){
  if (k == 0) return l;
  if (k == 1) return ((l & 63) << 6) | (l >> 6);
  if (k == 2) return (L_ - 1) - l;
  int lm = (L_ - 1) - l; return ((lm & 63) << 6) | (lm >> 6);
}

// ---------- layout shufflers ----------
__global__ void k_nchw2nhwc(const float* __restrict__ x, float* __restrict__ xf){
  long i = (long)blockIdx.x * 256 + threadIdx.x;      // over (b,l,c), c fast
  int c = (int)(i % 96); long p = i / 96; int b = (int)(p >> 12); int l = (int)(p & 4095);
  xf[i] = x[((long)b * 96 + c) * L_ + l];
}
__global__ void k_nhwc2nchw(const float* __restrict__ xf, float* __restrict__ out){
  long i = (long)blockIdx.x * 256 + threadIdx.x;      // over (b,c,l), l fast
  int l = (int)(i & 4095); long q = i >> 12; int c = (int)(q % 96); int b = (int)(q / 96);
  out[i] = xf[((long)b * L_ + l) * 96 + c];
}
__global__ void k_transpose(const float* __restrict__ w, float* __restrict__ wt, int rows, int cols){
  int t = blockIdx.x * 256 + threadIdx.x;
  if (t < rows * cols){ int r = t / cols, c = t % cols; wt[(long)c * rows + r] = w[t]; }
}

// ---------- layernorm over 96 channels (wave per pixel) ----------
__global__ void k_ln96(const float* __restrict__ in, float* __restrict__ out,
                       const float* __restrict__ g, const float* __restrict__ bb){
  int wave = threadIdx.x >> 6, lane = threadIdx.x & 63;
  long p = (long)blockIdx.x * 4 + wave;
  const float* row = in + p * 96;
  float v0 = row[lane];
  float v1 = (lane < 32) ? row[64 + lane] : 0.0f;
  float s  = wave_sum(v0 + v1);
  float sq = wave_sum(v0 * v0 + v1 * v1);
  float mean = s * (1.0f / 96.0f);
  float var  = sq * (1.0f / 96.0f) - mean * mean;
  float rs = rsqrtf(var + 1e-5f);
  out[p * 96 + lane] = (v0 - mean) * rs * g[lane] + bb[lane];
  if (lane < 32) out[p * 96 + 64 + lane] = (v1 - mean) * rs * g[64 + lane] + bb[64 + lane];
}

// ---------- in_proj: (B*L,96) x Wt(96,384) -> xz (B*L,384) ----------
__global__ void k_inproj(const float* __restrict__ h, const float* __restrict__ wt,
                         float* __restrict__ xz){
  __shared__ float hb[96];
  long p = blockIdx.x;
  int e = threadIdx.x;                 // 0..383
  if (e < 96) hb[e] = h[p * 96 + e];
  __syncthreads();
  float acc = 0.f;
  #pragma unroll 8
  for (int c = 0; c < 96; c++) acc += hb[c] * wt[(long)c * 384 + e];
  xz[p * 384 + e] = acc;
}

// ---------- depthwise 3x3 conv + bias + silu: xz(:, :192) -> u (B,Di,L) planar ----------
__global__ void k_dwconv(const float* __restrict__ xz, const float* __restrict__ cw,
                         const float* __restrict__ cb, float* __restrict__ u){
  int l = blockIdx.x * 64 + threadIdx.x;
  int d = blockIdx.y, b = blockIdx.z;
  int hh = l >> 6, ww = l & 63;
  float acc = cb[d];
  #pragma unroll
  for (int dh = -1; dh <= 1; dh++){
    int h2 = hh + dh; if (h2 < 0 || h2 >= 64) continue;
    #pragma unroll
    for (int dw = -1; dw <= 1; dw++){
      int w2 = ww + dw; if (w2 < 0 || w2 >= 64) continue;
      acc += xz[((long)b * L_ + h2 * 64 + w2) * 384 + d] * cw[d * 9 + (dh + 1) * 3 + (dw + 1)];
    }
  }
  u[((long)b * Di_ + d) * L_ + l] = siluf(acc);
}

// ---------- x_dbl[b,k,c,l] = sum_d u[b,d,idx_k(l)] * xw[k,c,d]  (c = 0..37) ----------
__global__ void k_xdbl(const float* __restrict__ u, const float* __restrict__ xw,
                       float* __restrict__ xd){
  int l = blockIdx.x * 256 + threadIdx.x;
  int bk = blockIdx.y; int b = bk >> 2, k = bk & 3;
  int idx = dir_idx(k, l);
  float acc[38];
  #pragma unroll
  for (int c = 0; c < 38; c++) acc[c] = 0.f;
  const float* ub = u + (long)b * Di_ * L_;
  const float* wb = xw + (long)k * 38 * Di_;
  for (int d = 0; d < Di_; d++){
    float uv = ub[(long)d * L_ + idx];
    #pragma unroll
    for (int c = 0; c < 38; c++) acc[c] += uv * wb[c * Di_ + d];
  }
  float* o = xd + (long)bk * 38 * L_ + l;
  #pragma unroll
  for (int c = 0; c < 38; c++) o[(long)c * L_] = acc[c];
}

// ================= chunked selective scan =================
// The recurrence h <- dA*h + dBu is affine in h, so it composes across chunks.
// Pass 1: per-chunk local scan from h=0 -> (P = prod dA, S = local final h).
// Pass 2: serial scan over the 32 chunks per state-lane -> Hin (incoming h).
// Pass 3: recompute local scan seeded with Hin, emit y (atomicAdd, 4 dirs).
// Wave layout: 4 d-channels x 16 states; block decode (b,k,dch,chunk).

__global__ void __launch_bounds__(64) k_scan1(
    const float* __restrict__ xd, const float* __restrict__ u,
    const float* __restrict__ Alog, const float* __restrict__ dtw,
    const float* __restrict__ dtb,
    float* __restrict__ P, float* __restrict__ S){
  int bid = blockIdx.x;
  int chunk = bid & (CH_ - 1); bid >>= 5;
  int dch = bid % 48; bid /= 48;
  int k = bid & 3, b = bid >> 2;
  int lane = threadIdx.x;
  int dsub = lane >> 4, n = lane & 15;
  int d = dch * 4 + dsub;
  int kd = k * Di_ + d;
  float Av = -__expf(Alog[(long)kd * 16 + n]);
  float w0 = dtw[kd*6+0], w1 = dtw[kd*6+1], w2 = dtw[kd*6+2];
  float w3 = dtw[kd*6+3], w4 = dtw[kd*6+4], w5 = dtw[kd*6+5];
  float bias = dtb[kd];
  const float* xb = xd + (long)(b * K_ + k) * 38 * L_;
  const float* ub = u + (long)(b * Di_ + d) * L_;
  float h = 0.f, pA = 1.f;
  int l0 = chunk * CL_;
  for (int l = l0; l < l0 + CL_; l++){
    int idx = dir_idx(k, l);
    float r0 = xb[l], r1 = xb[L_ + l], r2 = xb[2*L_ + l];
    float r3 = xb[3*L_ + l], r4 = xb[4*L_ + l], r5 = xb[5*L_ + l];
    float delta = softplusf(bias + w0*r0 + w1*r1 + w2*r2 + w3*r3 + w4*r4 + w5*r5);
    float uv = ub[idx];
    float bn = xb[(long)(6 + n) * L_ + l];
    float dA = __expf(delta * Av);
    h = dA * h + (delta * uv) * bn;
    pA *= dA;
  }
  int t = ((b * K_ + k) * Di_ + d) * 16 + n;   // 0..TL_-1
  P[(long)chunk * TL_ + t] = pA;
  S[(long)chunk * TL_ + t] = h;
}

__global__ void k_scan2(const float* __restrict__ P, const float* __restrict__ S,
                        float* __restrict__ Hin){
  int t = blockIdx.x * 256 + threadIdx.x;      // 0..TL_-1
  float h = 0.f;
  for (int c = 0; c < CH_; c++){
    Hin[(long)c * TL_ + t] = h;
    h = P[(long)c * TL_ + t] * h + S[(long)c * TL_ + t];
  }
}

__global__ void __launch_bounds__(64) k_scan3(
    const float* __restrict__ xd, const float* __restrict__ u,
    const float* __restrict__ Alog, const float* __restrict__ dtw,
    const float* __restrict__ dtb, const float* __restrict__ Dsk,
    const float* __restrict__ Hin, float* __restrict__ ycl){
  int bid = blockIdx.x;
  int chunk = bid & (CH_ - 1); bid >>= 5;
  int dch = bid % 48; bid /= 48;
  int k = bid & 3, b = bid >> 2;
  int lane = threadIdx.x;
  int dsub = lane >> 4, n = lane & 15;
  int d = dch * 4 + dsub;
  int kd = k * Di_ + d;
  float Av = -__expf(Alog[(long)kd * 16 + n]);
  float w0 = dtw[kd*6+0], w1 = dtw[kd*6+1], w2 = dtw[kd*6+2];
  float w3 = dtw[kd*6+3], w4 = dtw[kd*6+4], w5 = dtw[kd*6+5];
  float bias = dtb[kd];
  float Dv = Dsk[kd];
  const float* xb = xd + (long)(b * K_ + k) * 38 * L_;
  const float* ub = u + (long)(b * Di_ + d) * L_;
  float* yb = ycl + (long)b * L_ * Di_;
  int t = ((b * K_ + k) * Di_ + d) * 16 + n;
  float h = Hin[(long)chunk * TL_ + t];
  int l0 = chunk * CL_;
  for (int l = l0; l < l0 + CL_; l++){
    int idx = dir_idx(k, l);
    float r0 = xb[l], r1 = xb[L_ + l], r2 = xb[2*L_ + l];
    float r3 = xb[3*L_ + l], r4 = xb[4*L_ + l], r5 = xb[5*L_ + l];
    float delta = softplusf(bias + w0*r0 + w1*r1 + w2*r2 + w3*r3 + w4*r4 + w5*r5);
    float uv = ub[idx];
    float bn = xb[(long)(6  + n) * L_ + l];
    float cn = xb[(long)(22 + n) * L_ + l];
    float dA = __expf(delta * Av);
    h = dA * h + (delta * uv) * bn;
    float pr = h * cn;
    pr += __shfl_xor(pr, 1, 16);
    pr += __shfl_xor(pr, 2, 16);
    pr += __shfl_xor(pr, 4, 16);
    pr += __shfl_xor(pr, 8, 16);
    if (n == 0) atomicAdd(&yb[(long)idx * Di_ + d], pr + Dv * uv);
  }
}

// ---------- out_norm (LN over 192) * silu(z), in-place on ycl ----------
__global__ void k_outnorm(float* __restrict__ y, const float* __restrict__ xz,
                          const float* __restrict__ g, const float* __restrict__ bb){
  int wave = threadIdx.x >> 6, lane = threadIdx.x & 63;
  long p = (long)blockIdx.x * 4 + wave;
  float* row = y + p * 192;
  float v0 = row[lane], v1 = row[lane + 64], v2 = row[lane + 128];
  float s  = wave_sum(v0 + v1 + v2);
  float sq = wave_sum(v0*v0 + v1*v1 + v2*v2);
  float mean = s * (1.0f / 192.0f);
  float var  = sq * (1.0f / 192.0f) - mean * mean;
  float rs = rsqrtf(var + 1e-5f);
  const float* zr = xz + p * 384 + 192;
  row[lane]       = ((v0 - mean) * rs * g[lane]       + bb[lane])       * siluf(zr[lane]);
  row[lane + 64]  = ((v1 - mean) * rs * g[lane + 64]  + bb[lane + 64])  * siluf(zr[lane + 64]);
  row[lane + 128] = ((v2 - mean) * rs * g[lane + 128] + bb[lane + 128]) * siluf(zr[lane + 128]);
}

// ---------- out_proj (192->96) + skip1: xc = xf*skip1 + y @ Wt ----------
__global__ void k_outproj(const float* __restrict__ y, const float* __restrict__ wt,
                          const float* __restrict__ xf, const float* __restrict__ skip,
                          float* __restrict__ xc){
  __shared__ float yb[384];
  long p0 = (long)blockIdx.x * 2;
  int t = threadIdx.x;                  // 0..191
  yb[t]       = y[p0 * 192 + t];
  yb[t + 192] = y[(p0 + 1) * 192 + t];
  __syncthreads();
  int pp = t / 96, c = t % 96;
  long p = p0 + pp;
  float acc = 0.f;
  #pragma unroll 8
  for (int d = 0; d < 192; d++) acc += yb[pp * 192 + d] * wt[d * 96 + c];
  xc[p * 96 + c] = xf[p * 96 + c] * skip[c] + acc;
}

// ---------- CAB conv1 3x3 96->32 + exact gelu ----------
__global__ void k_cab1(const float* __restrict__ in, const float* __restrict__ w1,
                       const float* __restrict__ b1, float* __restrict__ t1){
  int t = threadIdx.x;
  int o = t & 31, pl = t >> 5;
  long pix = (long)blockIdx.x * 8 + pl;
  int b = (int)(pix >> 12); int l = (int)(pix & 4095);
  int hh = l >> 6, ww = l & 63;
  float acc = b1[o];
  for (int dh = -1; dh <= 1; dh++){
    int h2 = hh + dh; if (h2 < 0 || h2 >= 64) continue;
    for (int dw = -1; dw <= 1; dw++){
      int w2 = ww + dw; if (w2 < 0 || w2 >= 64) continue;
      const float* ir = in + ((long)b * L_ + h2 * 64 + w2) * 96;
      const float* wr = w1 + (long)o * 96 * 9 + (dh + 1) * 3 + (dw + 1);
      #pragma unroll 8
      for (int ci = 0; ci < 96; ci++) acc += ir[ci] * wr[ci * 9];
    }
  }
  t1[pix * 32 + o] = 0.5f * acc * (1.0f + erff(acc * 0.70710678118654752f));
}

// ---------- CAB conv2 3x3 32->96 (no activation) ----------
__global__ void k_cab2(const float* __restrict__ t1, const float* __restrict__ w2,
                       const float* __restrict__ b2, float* __restrict__ yc){
  int t = threadIdx.x;
  int o = t % 96, pl = t / 96;
  long pix = (long)blockIdx.x * 2 + pl;
  int b = (int)(pix >> 12); int l = (int)(pix & 4095);
  int hh = l >> 6, ww = l & 63;
  float acc = b2[o];
  for (int dh = -1; dh <= 1; dh++){
    int h2 = hh + dh; if (h2 < 0 || h2 >= 64) continue;
    for (int dw = -1; dw <= 1; dw++){
      int w2i = ww + dw; if (w2i < 0 || w2i >= 64) continue;
      const float* ir = t1 + ((long)b * L_ + h2 * 64 + w2i) * 32;
      const float* wr = w2 + (long)o * 32 * 9 + (dh + 1) * 3 + (dw + 1);
      #pragma unroll
      for (int ci = 0; ci < 32; ci++) acc += ir[ci] * wr[ci * 9];
    }
  }
  yc[pix * 96 + o] = acc;
}

// ---------- channel-attention: partial mean, then squeeze-excite ----------
__global__ void k_meanpart(const float* __restrict__ yc, float* __restrict__ part){
  int b = blockIdx.x >> 5, ch = blockIdx.x & 31;
  int o = threadIdx.x;
  float acc = 0.f;
  const float* base = yc + ((long)b * L_ + ch * 128) * 96 + o;
  for (int r = 0; r < 128; r++) acc += base[(long)r * 96];
  part[(long)blockIdx.x * 96 + o] = acc;
}
__global__ void k_attn(const float* __restrict__ part, const float* __restrict__ dw,
                       const float* __restrict__ db, const float* __restrict__ uw,
                       const float* __restrict__ ub, float* __restrict__ a){
  __shared__ float pv[96];
  __shared__ float tv[3];
  int b = blockIdx.x, o = threadIdx.x;
  float acc = 0.f;
  for (int ch = 0; ch < 32; ch++) acc += part[(long)(b * 32 + ch) * 96 + o];
  pv[o] = acc * (1.0f / 4096.0f);
  __syncthreads();
  if (o < 3){
    float t = db[o];
    for (int i2 = 0; i2 < 96; i2++) t += pv[i2] * dw[o * 96 + i2];
    tv[o] = t > 0.f ? t : 0.f;
  }
  __syncthreads();
  float av = ub[o] + tv[0] * uw[o * 3 + 0] + tv[1] * uw[o * 3 + 1] + tv[2] * uw[o * 3 + 2];
  a[b * 96 + o] = 1.0f / (1.0f + __expf(-av));
}

// ---------- final mix: xf = xc*skip2 + ycab*a ----------
__global__ void k_mix(const float* __restrict__ xc, const float* __restrict__ yc,
                      const float* __restrict__ a, const float* __restrict__ skip2,
                      float* __restrict__ xf){
  long i = (long)blockIdx.x * 256 + threadIdx.x;
  int c = (int)(i % 96); long p = i / 96; int b = (int)(p >> 12);
  xf[i] = xc[i] * skip2[c] + yc[i] * a[b * 96 + c];
}

extern "C" void kernel_launch(void* const* d_in, const int* in_sizes, int n_in,
                              void* d_out, int out_size, void* d_ws, size_t ws_size,
                              hipStream_t stream){
  const float* x          = (const float*)d_in[0];
  const float* ln1_g      = (const float*)d_in[1];
  const float* ln1_b      = (const float*)d_in[2];
  const float* in_proj_w  = (const float*)d_in[3];
  const float* conv_w     = (const float*)d_in[4];
  const float* conv_b     = (const float*)d_in[5];
  const float* x_proj_w   = (const float*)d_in[6];
  const float* dt_proj_w  = (const float*)d_in[7];
  const float* dt_proj_b  = (const float*)d_in[8];
  const float* A_logs     = (const float*)d_in[9];
  const float* Ds         = (const float*)d_in[10];
  const float* out_norm_g = (const float*)d_in[11];
  const float* out_norm_b = (const float*)d_in[12];
  const float* out_proj_w = (const float*)d_in[13];
  const float* skip1      = (const float*)d_in[14];
  const float* ln2_g      = (const float*)d_in[15];
  const float* ln2_b      = (const float*)d_in[16];
  const float* cab1_w     = (const float*)d_in[17];
  const float* cab1_b     = (const float*)d_in[18];
  const float* cab2_w     = (const float*)d_in[19];
  const float* cab2_b     = (const float*)d_in[20];
  const float* ca_dw      = (const float*)d_in[21];
  const float* ca_db      = (const float*)d_in[22];
  const float* ca_uw      = (const float*)d_in[23];
  const float* ca_ub      = (const float*)d_in[24];
  const float* skip2      = (const float*)d_in[25];

  float* W = (float*)d_ws;
  float* xf   = W + 0;         // 786432   (B,L,C)  current features
  float* hb   = W + 786432;    // 786432   ln output (reused ln1/ln2)
  float* xz   = W + 1572864;   // 3145728  (B,L,384) in_proj out (xp|z)
  float* u    = W + 4718592;   // 1572864  (B,Di,L) conv+silu
  float* xd   = W + 6291456;   // 1245184  (B,K,38,L)
  float* ycl  = W + 7536640;   // 1572864  (B,L,Di) scan accumulate / gated
  float* xc   = W + 9109504;   // 786432   (B,L,C)
  float* t1   = W + 9895936;   // 262144   (B,L,32)
  float* ycab = W + 10158080;  // 786432   (B,L,96)
  float* part = W + 10944512;  // 6144
  float* abuf = W + 10950656;  // 192
  float* wti  = W + 10950848;  // 36864    in_proj_w transposed (96,384)
  float* wto  = W + 10987712;  // 18432    out_proj_w transposed (192,96)
  // Scan chunk-state overlays (each CH_*TL_ = 786432 floats), reusing buffers
  // that are dead during the scan phase:
  //   P -> first half of ycl, S -> second half of ycl (consumed by k_scan2,
  //        then ycl is memset before k_scan3 writes into it)
  //   Hin -> xc (xc is only produced later by k_outproj)
  float* P   = ycl;
  float* S   = ycl + 786432;
  float* Hin = xc;

  k_nchw2nhwc<<<dim3(3072), dim3(256), 0, stream>>>(x, xf);

  for (int i = 0; i < 2; i++){
    const float* ipw  = in_proj_w  + (long)i * 384 * 96;
    const float* opw  = out_proj_w + (long)i * 96 * 192;
    const float* cw   = conv_w     + (long)i * 192 * 9;
    const float* cb   = conv_b     + (long)i * 192;
    const float* xpw  = x_proj_w   + (long)i * 4 * 38 * 192;
    const float* dtw  = dt_proj_w  + (long)i * 4 * 192 * 6;
    const float* dtbp = dt_proj_b  + (long)i * 4 * 192;
    const float* alog = A_logs     + (long)i * 768 * 16;
    const float* dsp  = Ds         + (long)i * 768;

    k_transpose<<<dim3(144), dim3(256), 0, stream>>>(ipw, wti, 384, 96);
    k_transpose<<<dim3(72),  dim3(256), 0, stream>>>(opw, wto, 96, 192);

    k_ln96<<<dim3(2048), dim3(256), 0, stream>>>(xf, hb, ln1_g + i*96, ln1_b + i*96);
    k_inproj<<<dim3(8192), dim3(384), 0, stream>>>(hb, wti, xz);
    k_dwconv<<<dim3(64, 192, 2), dim3(64), 0, stream>>>(xz, cw, cb, u);
    k_xdbl<<<dim3(16, 8), dim3(256), 0, stream>>>(u, xpw, xd);

    // chunked scan: pass1 -> (P,S), pass2 -> Hin, memset y, pass3 -> y
    k_scan1<<<dim3(12288), dim3(64), 0, stream>>>(xd, u, alog, dtw, dtbp, P, S);
    k_scan2<<<dim3(96), dim3(256), 0, stream>>>(P, S, Hin);
    hipMemsetAsync(ycl, 0, (size_t)1572864 * sizeof(float), stream);
    k_scan3<<<dim3(12288), dim3(64), 0, stream>>>(xd, u, alog, dtw, dtbp, dsp, Hin, ycl);

    k_outnorm<<<dim3(2048), dim3(256), 0, stream>>>(ycl, xz, out_norm_g + i*192, out_norm_b + i*192);
    k_outproj<<<dim3(4096), dim3(192), 0, stream>>>(ycl, wto, xf, skip1 + i*96, xc);

    k_ln96<<<dim3(2048), dim3(256), 0, stream>>>(xc, hb, ln2_g + i*96, ln2_b + i*96);
    k_cab1<<<dim3(1024), dim3(256), 0, stream>>>(hb, cab1_w + (long)i*32*96*9, cab1_b + i*32, t1);
    k_cab2<<<dim3(4096), dim3(192), 0, stream>>>(t1, cab2_w + (long)i*96*32*9, cab2_b + i*96, ycab);
    k_meanpart<<<dim3(64), dim3(96), 0, stream>>>(ycab, part);
    k_attn<<<dim3(2), dim3(96), 0, stream>>>(part, ca_dw + i*288, ca_db + i*3,
                                             ca_uw + i*288, ca_ub + i*96, abuf);
    k_mix<<<dim3(3072), dim3(256), 0, stream>>>(xc, ycab, abuf, skip2 + i*96, xf);
  }

  k_nhwc2nchw<<<dim3(3072), dim3(256), 0, stream>>>(xf, (float*)d_out);
}

// Round 3
// 2300.572 us; speedup vs baseline: 3.4731x; 1.7368x over previous
//
#include <hip/hip_runtime.h>
#include <math.h>

// Problem constants (fixed by the reference)
constexpr int B_  = 2;
constexpr int C_  = 96;     // DIM
constexpr int L_  = 4096;   // H*W
constexpr int Di_ = 192;    // D_INNER
constexpr int N_  = 16;     // D_STATE
constexpr int K_  = 4;      // directions
constexpr int CH_ = 32;     // scan chunks
constexpr int CL_ = 128;    // chunk length (CH_*CL_ == L_)
constexpr int TL_ = 24576;  // total state lanes = B*K*Di*N

__device__ __forceinline__ float siluf(float x){ return x / (1.0f + __expf(-x)); }
__device__ __forceinline__ float softplusf(float x){ return x > 15.0f ? x : log1pf(__expf(x)); }
__device__ __forceinline__ float wave_sum(float v){
  #pragma unroll
  for (int off = 32; off > 0; off >>= 1) v += __shfl_xor(v, off, 64);
  return v;
}
// direction index maps: scan position l -> row-major spatial index
__device__ __forceinline__ int dir_idx(int k, int l){
  if (k == 0) return l;
  if (k == 1) return ((l & 63) << 6) | (l >> 6);
  if (k == 2) return (L_ - 1) - l;
  int lm = (L_ - 1) - l; return ((lm & 63) << 6) | (lm >> 6);
}

// ---------- layout shufflers ----------
__global__ void k_nchw2nhwc(const float* __restrict__ x, float* __restrict__ xf){
  long i = (long)blockIdx.x * 256 + threadIdx.x;      // over (b,l,c), c fast
  int c = (int)(i % 96); long p = i / 96; int b = (int)(p >> 12); int l = (int)(p & 4095);
  xf[i] = x[((long)b * 96 + c) * L_ + l];
}
__global__ void k_nhwc2nchw(const float* __restrict__ xf, float* __restrict__ out){
  long i = (long)blockIdx.x * 256 + threadIdx.x;      // over (b,c,l), l fast
  int l = (int)(i & 4095); long q = i >> 12; int c = (int)(q % 96); int b = (int)(q / 96);
  out[i] = xf[((long)b * L_ + l) * 96 + c];
}
__global__ void k_transpose(const float* __restrict__ w, float* __restrict__ wt, int rows, int cols){
  int t = blockIdx.x * 256 + threadIdx.x;
  if (t < rows * cols){ int r = t / cols, c = t % cols; wt[(long)c * rows + r] = w[t]; }
}
// conv weight [O][I][3][3] -> [tap][I][O]  (lane-contiguous in O)
__global__ void k_wconv_t(const float* __restrict__ w, float* __restrict__ wt, int O, int I){
  int t = blockIdx.x * 256 + threadIdx.x;
  int tot = O * I * 9;
  if (t < tot){
    int tap = t % 9; int rem = t / 9;
    int ci = rem % I; int o = rem / I;
    wt[(tap * I + ci) * O + o] = w[t];
  }
}

// ---------- layernorm over 96 channels (wave per pixel) ----------
__global__ void k_ln96(const float* __restrict__ in, float* __restrict__ out,
                       const float* __restrict__ g, const float* __restrict__ bb){
  int wave = threadIdx.x >> 6, lane = threadIdx.x & 63;
  long p = (long)blockIdx.x * 4 + wave;
  const float* row = in + p * 96;
  float v0 = row[lane];
  float v1 = (lane < 32) ? row[64 + lane] : 0.0f;
  float s  = wave_sum(v0 + v1);
  float sq = wave_sum(v0 * v0 + v1 * v1);
  float mean = s * (1.0f / 96.0f);
  float var  = sq * (1.0f / 96.0f) - mean * mean;
  float rs = rsqrtf(var + 1e-5f);
  out[p * 96 + lane] = (v0 - mean) * rs * g[lane] + bb[lane];
  if (lane < 32) out[p * 96 + 64 + lane] = (v1 - mean) * rs * g[64 + lane] + bb[64 + lane];
}

// ---------- in_proj: (B*L,96) x Wt(96,384) -> xz (B*L,384) ----------
__global__ void k_inproj(const float* __restrict__ h, const float* __restrict__ wt,
                         float* __restrict__ xz){
  __shared__ float hb[96];
  long p = blockIdx.x;
  int e = threadIdx.x;                 // 0..383
  if (e < 96) hb[e] = h[p * 96 + e];
  __syncthreads();
  float acc = 0.f;
  #pragma unroll 8
  for (int c = 0; c < 96; c++) acc += hb[c] * wt[(long)c * 384 + e];
  xz[p * 384 + e] = acc;
}

// ---------- depthwise 3x3 conv + bias + silu: xz(:, :192) -> u (B,Di,L) planar ----------
__global__ void k_dwconv(const float* __restrict__ xz, const float* __restrict__ cw,
                         const float* __restrict__ cb, float* __restrict__ u){
  int l = blockIdx.x * 64 + threadIdx.x;
  int d = blockIdx.y, b = blockIdx.z;
  int hh = l >> 6, ww = l & 63;
  float acc = cb[d];
  #pragma unroll
  for (int dh = -1; dh <= 1; dh++){
    int h2 = hh + dh; if (h2 < 0 || h2 >= 64) continue;
    #pragma unroll
    for (int dw = -1; dw <= 1; dw++){
      int w2 = ww + dw; if (w2 < 0 || w2 >= 64) continue;
      acc += xz[((long)b * L_ + h2 * 64 + w2) * 384 + d] * cw[d * 9 + (dh + 1) * 3 + (dw + 1)];
    }
  }
  u[((long)b * Di_ + d) * L_ + l] = siluf(acc);
}

// ---------- x_dbl[b,k,c,l] = sum_d u[b,d,idx_k(l)] * xw[k,c,d]  (c = 0..37) ----------
__global__ void k_xdbl(const float* __restrict__ u, const float* __restrict__ xw,
                       float* __restrict__ xd){
  int l = blockIdx.x * 256 + threadIdx.x;
  int bk = blockIdx.y; int b = bk >> 2, k = bk & 3;
  int idx = dir_idx(k, l);
  float acc[38];
  #pragma unroll
  for (int c = 0; c < 38; c++) acc[c] = 0.f;
  const float* ub = u + (long)b * Di_ * L_;
  const float* wb = xw + (long)k * 38 * Di_;
  for (int d = 0; d < Di_; d++){
    float uv = ub[(long)d * L_ + idx];
    #pragma unroll
    for (int c = 0; c < 38; c++) acc[c] += uv * wb[c * Di_ + d];
  }
  float* o = xd + (long)bk * 38 * L_ + l;
  #pragma unroll
  for (int c = 0; c < 38; c++) o[(long)c * L_] = acc[c];
}

// ================= chunked selective scan =================
__global__ void __launch_bounds__(64) k_scan1(
    const float* __restrict__ xd, const float* __restrict__ u,
    const float* __restrict__ Alog, const float* __restrict__ dtw,
    const float* __restrict__ dtb,
    float* __restrict__ P, float* __restrict__ S){
  int bid = blockIdx.x;
  int chunk = bid & (CH_ - 1); bid >>= 5;
  int dch = bid % 48; bid /= 48;
  int k = bid & 3, b = bid >> 2;
  int lane = threadIdx.x;
  int dsub = lane >> 4, n = lane & 15;
  int d = dch * 4 + dsub;
  int kd = k * Di_ + d;
  float Av = -__expf(Alog[(long)kd * 16 + n]);
  float w0 = dtw[kd*6+0], w1 = dtw[kd*6+1], w2 = dtw[kd*6+2];
  float w3 = dtw[kd*6+3], w4 = dtw[kd*6+4], w5 = dtw[kd*6+5];
  float bias = dtb[kd];
  const float* xb = xd + (long)(b * K_ + k) * 38 * L_;
  const float* ub = u + (long)(b * Di_ + d) * L_;
  float h = 0.f, pA = 1.f;
  int l0 = chunk * CL_;
  for (int l = l0; l < l0 + CL_; l++){
    int idx = dir_idx(k, l);
    float r0 = xb[l], r1 = xb[L_ + l], r2 = xb[2*L_ + l];
    float r3 = xb[3*L_ + l], r4 = xb[4*L_ + l], r5 = xb[5*L_ + l];
    float delta = softplusf(bias + w0*r0 + w1*r1 + w2*r2 + w3*r3 + w4*r4 + w5*r5);
    float uv = ub[idx];
    float bn = xb[(long)(6 + n) * L_ + l];
    float dA = __expf(delta * Av);
    h = dA * h + (delta * uv) * bn;
    pA *= dA;
  }
  int t = ((b * K_ + k) * Di_ + d) * 16 + n;   // 0..TL_-1
  P[(long)chunk * TL_ + t] = pA;
  S[(long)chunk * TL_ + t] = h;
}

__global__ void k_scan2(const float* __restrict__ P, const float* __restrict__ S,
                        float* __restrict__ Hin){
  int t = blockIdx.x * 256 + threadIdx.x;      // 0..TL_-1
  float h = 0.f;
  for (int c = 0; c < CH_; c++){
    Hin[(long)c * TL_ + t] = h;
    h = P[(long)c * TL_ + t] * h + S[(long)c * TL_ + t];
  }
}

__global__ void __launch_bounds__(64) k_scan3(
    const float* __restrict__ xd, const float* __restrict__ u,
    const float* __restrict__ Alog, const float* __restrict__ dtw,
    const float* __restrict__ dtb, const float* __restrict__ Dsk,
    const float* __restrict__ Hin, float* __restrict__ ycl){
  int bid = blockIdx.x;
  int chunk = bid & (CH_ - 1); bid >>= 5;
  int dch = bid % 48; bid /= 48;
  int k = bid & 3, b = bid >> 2;
  int lane = threadIdx.x;
  int dsub = lane >> 4, n = lane & 15;
  int d = dch * 4 + dsub;
  int kd = k * Di_ + d;
  float Av = -__expf(Alog[(long)kd * 16 + n]);
  float w0 = dtw[kd*6+0], w1 = dtw[kd*6+1], w2 = dtw[kd*6+2];
  float w3 = dtw[kd*6+3], w4 = dtw[kd*6+4], w5 = dtw[kd*6+5];
  float bias = dtb[kd];
  float Dv = Dsk[kd];
  const float* xb = xd + (long)(b * K_ + k) * 38 * L_;
  const float* ub = u + (long)(b * Di_ + d) * L_;
  float* yb = ycl + (long)b * L_ * Di_;
  int t = ((b * K_ + k) * Di_ + d) * 16 + n;
  float h = Hin[(long)chunk * TL_ + t];
  int l0 = chunk * CL_;
  for (int l = l0; l < l0 + CL_; l++){
    int idx = dir_idx(k, l);
    float r0 = xb[l], r1 = xb[L_ + l], r2 = xb[2*L_ + l];
    float r3 = xb[3*L_ + l], r4 = xb[4*L_ + l], r5 = xb[5*L_ + l];
    float delta = softplusf(bias + w0*r0 + w1*r1 + w2*r2 + w3*r3 + w4*r4 + w5*r5);
    float uv = ub[idx];
    float bn = xb[(long)(6  + n) * L_ + l];
    float cn = xb[(long)(22 + n) * L_ + l];
    float dA = __expf(delta * Av);
    h = dA * h + (delta * uv) * bn;
    float pr = h * cn;
    pr += __shfl_xor(pr, 1, 16);
    pr += __shfl_xor(pr, 2, 16);
    pr += __shfl_xor(pr, 4, 16);
    pr += __shfl_xor(pr, 8, 16);
    if (n == 0) atomicAdd(&yb[(long)idx * Di_ + d], pr + Dv * uv);
  }
}

// ---------- out_norm (LN over 192) * silu(z), in-place on ycl ----------
__global__ void k_outnorm(float* __restrict__ y, const float* __restrict__ xz,
                          const float* __restrict__ g, const float* __restrict__ bb){
  int wave = threadIdx.x >> 6, lane = threadIdx.x & 63;
  long p = (long)blockIdx.x * 4 + wave;
  float* row = y + p * 192;
  float v0 = row[lane], v1 = row[lane + 64], v2 = row[lane + 128];
  float s  = wave_sum(v0 + v1 + v2);
  float sq = wave_sum(v0*v0 + v1*v1 + v2*v2);
  float mean = s * (1.0f / 192.0f);
  float var  = sq * (1.0f / 192.0f) - mean * mean;
  float rs = rsqrtf(var + 1e-5f);
  const float* zr = xz + p * 384 + 192;
  row[lane]       = ((v0 - mean) * rs * g[lane]       + bb[lane])       * siluf(zr[lane]);
  row[lane + 64]  = ((v1 - mean) * rs * g[lane + 64]  + bb[lane + 64])  * siluf(zr[lane + 64]);
  row[lane + 128] = ((v2 - mean) * rs * g[lane + 128] + bb[lane + 128]) * siluf(zr[lane + 128]);
}

// ---------- out_proj (192->96) + skip1: xc = xf*skip1 + y @ Wt ----------
__global__ void k_outproj(const float* __restrict__ y, const float* __restrict__ wt,
                          const float* __restrict__ xf, const float* __restrict__ skip,
                          float* __restrict__ xc){
  __shared__ float yb[384];
  long p0 = (long)blockIdx.x * 2;
  int t = threadIdx.x;                  // 0..191
  yb[t]       = y[p0 * 192 + t];
  yb[t + 192] = y[(p0 + 1) * 192 + t];
  __syncthreads();
  int pp = t / 96, c = t % 96;
  long p = p0 + pp;
  float acc = 0.f;
  #pragma unroll 8
  for (int d = 0; d < 192; d++) acc += yb[pp * 192 + d] * wt[d * 96 + c];
  xc[p * 96 + c] = xf[p * 96 + c] * skip[c] + acc;
}

// ---------- CAB conv1 3x3 96->32 + exact gelu (weights pre-transposed [tap][ci][o]) ----------
__global__ void k_cab1(const float* __restrict__ in, const float* __restrict__ w1t,
                       const float* __restrict__ b1, float* __restrict__ t1){
  int t = threadIdx.x;
  int o = t & 31, pl = t >> 5;
  long pix = (long)blockIdx.x * 8 + pl;
  int b = (int)(pix >> 12); int l = (int)(pix & 4095);
  int hh = l >> 6, ww = l & 63;
  float acc = b1[o];
  for (int dh = -1; dh <= 1; dh++){
    int h2 = hh + dh; if (h2 < 0 || h2 >= 64) continue;
    for (int dw = -1; dw <= 1; dw++){
      int w2 = ww + dw; if (w2 < 0 || w2 >= 64) continue;
      const float* ir = in + ((long)b * L_ + h2 * 64 + w2) * 96;
      const float* wr = w1t + (long)((dh + 1) * 3 + (dw + 1)) * 96 * 32 + o;
      #pragma unroll 8
      for (int ci = 0; ci < 96; ci++) acc += ir[ci] * wr[ci * 32];
    }
  }
  t1[pix * 32 + o] = 0.5f * acc * (1.0f + erff(acc * 0.70710678118654752f));
}

// ---------- CAB conv2 3x3 32->96 (weights pre-transposed [tap][ci][o]) ----------
__global__ void k_cab2(const float* __restrict__ t1, const float* __restrict__ w2t,
                       const float* __restrict__ b2, float* __restrict__ yc){
  int t = threadIdx.x;
  int o = t % 96, pl = t / 96;
  long pix = (long)blockIdx.x * 2 + pl;
  int b = (int)(pix >> 12); int l = (int)(pix & 4095);
  int hh = l >> 6, ww = l & 63;
  float acc = b2[o];
  for (int dh = -1; dh <= 1; dh++){
    int h2 = hh + dh; if (h2 < 0 || h2 >= 64) continue;
    for (int dw = -1; dw <= 1; dw++){
      int w2i = ww + dw; if (w2i < 0 || w2i >= 64) continue;
      const float* ir = t1 + ((long)b * L_ + h2 * 64 + w2i) * 32;
      const float* wr = w2t + (long)((dh + 1) * 3 + (dw + 1)) * 32 * 96 + o;
      #pragma unroll
      for (int ci = 0; ci < 32; ci++) acc += ir[ci] * wr[ci * 96];
    }
  }
  yc[pix * 96 + o] = acc;
}

// ---------- channel-attention: partial mean, then squeeze-excite ----------
__global__ void k_meanpart(const float* __restrict__ yc, float* __restrict__ part){
  int b = blockIdx.x >> 5, ch = blockIdx.x & 31;
  int o = threadIdx.x;
  float acc = 0.f;
  const float* base = yc + ((long)b * L_ + ch * 128) * 96 + o;
  for (int r = 0; r < 128; r++) acc += base[(long)r * 96];
  part[(long)blockIdx.x * 96 + o] = acc;
}
__global__ void k_attn(const float* __restrict__ part, const float* __restrict__ dw,
                       const float* __restrict__ db, const float* __restrict__ uw,
                       const float* __restrict__ ub, float* __restrict__ a){
  __shared__ float pv[96];
  __shared__ float tv[3];
  int b = blockIdx.x, o = threadIdx.x;
  float acc = 0.f;
  for (int ch = 0; ch < 32; ch++) acc += part[(long)(b * 32 + ch) * 96 + o];
  pv[o] = acc * (1.0f / 4096.0f);
  __syncthreads();
  if (o < 3){
    float t = db[o];
    for (int i2 = 0; i2 < 96; i2++) t += pv[i2] * dw[o * 96 + i2];
    tv[o] = t > 0.f ? t : 0.f;
  }
  __syncthreads();
  float av = ub[o] + tv[0] * uw[o * 3 + 0] + tv[1] * uw[o * 3 + 1] + tv[2] * uw[o * 3 + 2];
  a[b * 96 + o] = 1.0f / (1.0f + __expf(-av));
}

// ---------- final mix: xf = xc*skip2 + ycab*a ----------
__global__ void k_mix(const float* __restrict__ xc, const float* __restrict__ yc,
                      const float* __restrict__ a, const float* __restrict__ skip2,
                      float* __restrict__ xf){
  long i = (long)blockIdx.x * 256 + threadIdx.x;
  int c = (int)(i % 96); long p = i / 96; int b = (int)(p >> 12);
  xf[i] = xc[i] * skip2[c] + yc[i] * a[b * 96 + c];
}

extern "C" void kernel_launch(void* const* d_in, const int* in_sizes, int n_in,
                              void* d_out, int out_size, void* d_ws, size_t ws_size,
                              hipStream_t stream){
  const float* x          = (const float*)d_in[0];
  const float* ln1_g      = (const float*)d_in[1];
  const float* ln1_b      = (const float*)d_in[2];
  const float* in_proj_w  = (const float*)d_in[3];
  const float* conv_w     = (const float*)d_in[4];
  const float* conv_b     = (const float*)d_in[5];
  const float* x_proj_w   = (const float*)d_in[6];
  const float* dt_proj_w  = (const float*)d_in[7];
  const float* dt_proj_b  = (const float*)d_in[8];
  const float* A_logs     = (const float*)d_in[9];
  const float* Ds         = (const float*)d_in[10];
  const float* out_norm_g = (const float*)d_in[11];
  const float* out_norm_b = (const float*)d_in[12];
  const float* out_proj_w = (const float*)d_in[13];
  const float* skip1      = (const float*)d_in[14];
  const float* ln2_g      = (const float*)d_in[15];
  const float* ln2_b      = (const float*)d_in[16];
  const float* cab1_w     = (const float*)d_in[17];
  const float* cab1_b     = (const float*)d_in[18];
  const float* cab2_w     = (const float*)d_in[19];
  const float* cab2_b     = (const float*)d_in[20];
  const float* ca_dw      = (const float*)d_in[21];
  const float* ca_db      = (const float*)d_in[22];
  const float* ca_uw      = (const float*)d_in[23];
  const float* ca_ub      = (const float*)d_in[24];
  const float* skip2      = (const float*)d_in[25];

  float* W = (float*)d_ws;
  float* xf   = W + 0;         // 786432   (B,L,C)  current features
  float* hb   = W + 786432;    // 786432   ln output (reused ln1/ln2)
  float* xz   = W + 1572864;   // 3145728  (B,L,384) in_proj out (xp|z)
  float* u    = W + 4718592;   // 1572864  (B,Di,L) conv+silu
  float* xd   = W + 6291456;   // 1245184  (B,K,38,L)
  float* ycl  = W + 7536640;   // 1572864  (B,L,Di) scan accumulate / gated
  float* xc   = W + 9109504;   // 786432   (B,L,C)
  float* t1   = W + 9895936;   // 262144   (B,L,32)
  float* ycab = W + 10158080;  // 786432   (B,L,96)
  float* part = W + 10944512;  // 6144
  float* abuf = W + 10950656;  // 192
  float* wti  = W + 10950848;  // 36864    in_proj_w transposed (96,384)
  float* wto  = W + 10987712;  // 18432    out_proj_w transposed (192,96)
  float* wt1  = W + 11006144;  // 27648    cab1_w transposed [tap][96][32]
  float* wt2  = W + 11033792;  // 27648    cab2_w transposed [tap][32][96]
  // Scan chunk-state overlays (each CH_*TL_ = 786432 floats), reusing buffers
  // that are dead during the scan phase.
  float* P   = ycl;
  float* S   = ycl + 786432;
  float* Hin = xc;

  k_nchw2nhwc<<<dim3(3072), dim3(256), 0, stream>>>(x, xf);

  for (int i = 0; i < 2; i++){
    const float* ipw  = in_proj_w  + (long)i * 384 * 96;
    const float* opw  = out_proj_w + (long)i * 96 * 192;
    const float* cw   = conv_w     + (long)i * 192 * 9;
    const float* cb   = conv_b     + (long)i * 192;
    const float* xpw  = x_proj_w   + (long)i * 4 * 38 * 192;
    const float* dtw  = dt_proj_w  + (long)i * 4 * 192 * 6;
    const float* dtbp = dt_proj_b  + (long)i * 4 * 192;
    const float* alog = A_logs     + (long)i * 768 * 16;
    const float* dsp  = Ds         + (long)i * 768;

    k_transpose<<<dim3(144), dim3(256), 0, stream>>>(ipw, wti, 384, 96);
    k_transpose<<<dim3(72),  dim3(256), 0, stream>>>(opw, wto, 96, 192);
    k_wconv_t<<<dim3(108), dim3(256), 0, stream>>>(cab1_w + (long)i*32*96*9, wt1, 32, 96);
    k_wconv_t<<<dim3(108), dim3(256), 0, stream>>>(cab2_w + (long)i*96*32*9, wt2, 96, 32);

    k_ln96<<<dim3(2048), dim3(256), 0, stream>>>(xf, hb, ln1_g + i*96, ln1_b + i*96);
    k_inproj<<<dim3(8192), dim3(384), 0, stream>>>(hb, wti, xz);
    k_dwconv<<<dim3(64, 192, 2), dim3(64), 0, stream>>>(xz, cw, cb, u);
    k_xdbl<<<dim3(16, 8), dim3(256), 0, stream>>>(u, xpw, xd);

    // chunked scan: pass1 -> (P,S), pass2 -> Hin, memset y, pass3 -> y
    k_scan1<<<dim3(12288), dim3(64), 0, stream>>>(xd, u, alog, dtw, dtbp, P, S);
    k_scan2<<<dim3(96), dim3(256), 0, stream>>>(P, S, Hin);
    hipMemsetAsync(ycl, 0, (size_t)1572864 * sizeof(float), stream);
    k_scan3<<<dim3(12288), dim3(64), 0, stream>>>(xd, u, alog, dtw, dtbp, dsp, Hin, ycl);

    k_outnorm<<<dim3(2048), dim3(256), 0, stream>>>(ycl, xz, out_norm_g + i*192, out_norm_b + i*192);
    k_outproj<<<dim3(4096), dim3(192), 0, stream>>>(ycl, wto, xf, skip1 + i*96, xc);

    k_ln96<<<dim3(2048), dim3(256), 0, stream>>>(xc, hb, ln2_g + i*96, ln2_b + i*96);
    k_cab1<<<dim3(1024), dim3(256), 0, stream>>>(hb, wt1, cab1_b + i*32, t1);
    k_cab2<<<dim3(4096), dim3(192), 0, stream>>>(t1, wt2, cab2_b + i*96, ycab);
    k_meanpart<<<dim3(64), dim3(96), 0, stream>>>(ycab, part);
    k_attn<<<dim3(2), dim3(96), 0, stream>>>(part, ca_dw + i*288, ca_db + i*3,
                                             ca_uw + i*288, ca_ub + i*96, abuf);
    k_mix<<<dim3(3072), dim3(256), 0, stream>>>(xc, ycab, abuf, skip2 + i*96, xf);
  }

  k_nhwc2nchw<<<dim3(3072), dim3(256), 0, stream>>>(xf, (float*)d_out);
}

// Round 4
// 1041.621 us; speedup vs baseline: 7.6707x; 2.2086x over previous
//
#include <hip/hip_runtime.h>
#include <math.h>

// Problem constants (fixed by the reference)
constexpr int B_  = 2;
constexpr int L_  = 4096;   // H*W
constexpr int Di_ = 192;    // D_INNER
constexpr int K_  = 4;      // directions
constexpr int CH_ = 32;     // scan chunks
constexpr int CL_ = 128;    // chunk length (CH_*CL_ == L_)
constexpr int TL_ = 24576;  // total state lanes = B*K*Di*N
constexpr int RW_ = 40;     // xd row stride: [B(16) | C(16) | dt(6) | pad(2)]

__device__ __forceinline__ float siluf(float x){ return x / (1.0f + __expf(-x)); }
__device__ __forceinline__ float softplus_fast(float x){
  return x > 15.0f ? x : __logf(1.0f + __expf(x));
}
__device__ __forceinline__ float wave_sum(float v){
  #pragma unroll
  for (int off = 32; off > 0; off >>= 1) v += __shfl_xor(v, off, 64);
  return v;
}
// direction index maps: scan position l -> row-major spatial index
__device__ __forceinline__ int dir_idx(int k, int l){
  if (k == 0) return l;
  if (k == 1) return ((l & 63) << 6) | (l >> 6);
  if (k == 2) return (L_ - 1) - l;
  int lm = (L_ - 1) - l; return ((lm & 63) << 6) | (lm >> 6);
}

// ---------- layout shufflers ----------
__global__ void k_nchw2nhwc(const float* __restrict__ x, float* __restrict__ xf){
  long i = (long)blockIdx.x * 256 + threadIdx.x;
  int c = (int)(i % 96); long p = i / 96; int b = (int)(p >> 12); int l = (int)(p & 4095);
  xf[i] = x[((long)b * 96 + c) * L_ + l];
}
__global__ void k_nhwc2nchw(const float* __restrict__ xf, float* __restrict__ out){
  long i = (long)blockIdx.x * 256 + threadIdx.x;
  int l = (int)(i & 4095); long q = i >> 12; int c = (int)(q % 96); int b = (int)(q / 96);
  out[i] = xf[((long)b * L_ + l) * 96 + c];
}
__global__ void k_transpose(const float* __restrict__ w, float* __restrict__ wt, int rows, int cols){
  int t = blockIdx.x * 256 + threadIdx.x;
  if (t < rows * cols){ int r = t / cols, c = t % cols; wt[(long)c * rows + r] = w[t]; }
}
// conv weight [O][I][3][3] -> [tap][I][O]  (lane-contiguous in O)
__global__ void k_wconv_t(const float* __restrict__ w, float* __restrict__ wt, int O, int I){
  int t = blockIdx.x * 256 + threadIdx.x;
  int tot = O * I * 9;
  if (t < tot){
    int tap = t % 9; int rem = t / 9;
    int ci = rem % I; int o = rem / I;
    wt[(tap * I + ci) * O + o] = w[t];
  }
}

// ---------- layernorm over 96 channels (wave per pixel) ----------
__global__ void k_ln96(const float* __restrict__ in, float* __restrict__ out,
                       const float* __restrict__ g, const float* __restrict__ bb){
  int wave = threadIdx.x >> 6, lane = threadIdx.x & 63;
  long p = (long)blockIdx.x * 4 + wave;
  const float* row = in + p * 96;
  float v0 = row[lane];
  float v1 = (lane < 32) ? row[64 + lane] : 0.0f;
  float s  = wave_sum(v0 + v1);
  float sq = wave_sum(v0 * v0 + v1 * v1);
  float mean = s * (1.0f / 96.0f);
  float var  = sq * (1.0f / 96.0f) - mean * mean;
  float rs = rsqrtf(var + 1e-5f);
  out[p * 96 + lane] = (v0 - mean) * rs * g[lane] + bb[lane];
  if (lane < 32) out[p * 96 + 64 + lane] = (v1 - mean) * rs * g[64 + lane] + bb[64 + lane];
}

// ---------- in_proj: (B*L,96) x Wt(96,384) -> xz (B*L,384) ----------
__global__ void k_inproj(const float* __restrict__ h, const float* __restrict__ wt,
                         float* __restrict__ xz){
  __shared__ float hb[96];
  long p = blockIdx.x;
  int e = threadIdx.x;                 // 0..383
  if (e < 96) hb[e] = h[p * 96 + e];
  __syncthreads();
  float acc = 0.f;
  #pragma unroll 8
  for (int c = 0; c < 96; c++) acc += hb[c] * wt[(long)c * 384 + e];
  xz[p * 384 + e] = acc;
}

// ---------- depthwise 3x3 conv + bias + silu -> u_t (B,L,Di) channel-last ----------
// thread = channel d (coalesced reads of xz row, coalesced writes of u_t row)
__global__ void k_dwconv(const float* __restrict__ xz, const float* __restrict__ cwt,
                         const float* __restrict__ cb, float* __restrict__ u_t){
  int tid = threadIdx.x;               // 0..383  (2 pixels x 192 ch)
  int d = tid % 192, px = tid / 192;
  int l = blockIdx.x * 2 + px;
  int b = blockIdx.y;
  int hh = l >> 6, ww = l & 63;
  float acc = cb[d];
  #pragma unroll
  for (int tap = 0; tap < 9; tap++){
    int dh = tap / 3 - 1, dw = tap % 3 - 1;
    int h2 = hh + dh, w2 = ww + dw;
    if (h2 < 0 || h2 >= 64 || w2 < 0 || w2 >= 64) continue;
    acc += xz[((long)(b * L_ + h2 * 64 + w2)) * 384 + d] * cwt[tap * 192 + d];
  }
  u_t[((long)b * L_ + l) * 192 + d] = siluf(acc);
}

// ---------- x_dbl rows: xd2[(b,k,l)][RW_] with layout [B16|C16|dt6|pad2] ----------
// LDS-tiled: 64 gathered u_t rows staged, then 64l x 38c x 192d mini-GEMM.
__global__ void __launch_bounds__(256) k_xdbl(const float* __restrict__ u_t,
                                              const float* __restrict__ xw,
                                              float* __restrict__ xd2){
  __shared__ float su[64][193];        // stride 193 (odd) -> conflict-free
  int bk = blockIdx.y; int b = bk >> 2, k = bk & 3;
  int l0 = blockIdx.x * 64;
  int tid = threadIdx.x;
  for (int e = tid; e < 64 * 192; e += 256){
    int r = e / 192, d = e - r * 192;
    su[r][d] = u_t[((long)b * L_ + dir_idx(k, l0 + r)) * 192 + d];
  }
  __syncthreads();
  int lsub = tid & 63, cg = tid >> 6;  // cg 0..3
  const float* wb = xw + (long)k * 38 * 192;
  float acc[10];
  #pragma unroll
  for (int j = 0; j < 10; j++) acc[j] = 0.f;
  int nj = (cg < 2) ? 10 : 9;
  for (int d = 0; d < 192; d++){
    float uv = su[lsub][d];
    #pragma unroll
    for (int j = 0; j < 10; j++){
      int c = 4 * j + cg;
      if (c < 38) acc[j] += uv * wb[c * 192 + d];
    }
  }
  float* rowp = xd2 + ((long)bk * L_ + (l0 + lsub)) * RW_;
  for (int j = 0; j < nj; j++){
    int c = 4 * j + cg;
    int pos = (c < 6) ? 32 + c : c - 6;  // dt rows -> 32..37, B -> 0..15, C -> 16..31
    rowp[pos] = acc[j];
  }
}

// ================= chunked selective scan (wave = 16 d x 4 n, 4 states/lane) ======
__global__ void __launch_bounds__(64) k_scan1(
    const float* __restrict__ xd2, const float* __restrict__ u_t,
    const float* __restrict__ Alog, const float* __restrict__ dtw,
    const float* __restrict__ dtb,
    float* __restrict__ P, float* __restrict__ S){
  int bid = blockIdx.x;
  int chunk = bid & (CH_ - 1); bid >>= 5;
  int dg = bid % 12; bid /= 12;
  int k = bid & 3, b = bid >> 2;
  int lane = threadIdx.x;
  int dgrp = lane >> 2, nsub = lane & 3;
  int d = dg * 16 + dgrp;
  int n0 = nsub * 4;
  int kd = k * 192 + d;
  float Av0 = -__expf(Alog[kd * 16 + n0 + 0]);
  float Av1 = -__expf(Alog[kd * 16 + n0 + 1]);
  float Av2 = -__expf(Alog[kd * 16 + n0 + 2]);
  float Av3 = -__expf(Alog[kd * 16 + n0 + 3]);
  float w0 = dtw[kd*6+0], w1 = dtw[kd*6+1], w2 = dtw[kd*6+2];
  float w3 = dtw[kd*6+3], w4 = dtw[kd*6+4], w5 = dtw[kd*6+5];
  float bias = dtb[kd];
  const float* xrow = xd2 + (long)(b * K_ + k) * L_ * RW_;
  const float* ub = u_t + (long)b * L_ * 192 + d;
  float h0=0,h1=0,h2=0,h3=0, p0=1,p1=1,p2=1,p3=1;
  int l0 = chunk * CL_;
  for (int l = l0; l < l0 + CL_; l++){
    const float* rp = xrow + (long)l * RW_;
    float4 ra = *(const float4*)(rp + 32);
    float2 rb = *(const float2*)(rp + 36);
    float4 bn = *(const float4*)(rp + n0);
    float dlt = softplus_fast(bias + w0*ra.x + w1*ra.y + w2*ra.z + w3*ra.w + w4*rb.x + w5*rb.y);
    float uv = ub[(long)dir_idx(k, l) * 192];
    float du = dlt * uv;
    float a0 = __expf(dlt * Av0), a1 = __expf(dlt * Av1);
    float a2 = __expf(dlt * Av2), a3 = __expf(dlt * Av3);
    h0 = a0*h0 + du*bn.x; h1 = a1*h1 + du*bn.y;
    h2 = a2*h2 + du*bn.z; h3 = a3*h3 + du*bn.w;
    p0 *= a0; p1 *= a1; p2 *= a2; p3 *= a3;
  }
  long t = (long)((b * K_ + k) * 192 + d) * 16 + n0;
  *(float4*)&P[(long)chunk * TL_ + t] = make_float4(p0, p1, p2, p3);
  *(float4*)&S[(long)chunk * TL_ + t] = make_float4(h0, h1, h2, h3);
}

__global__ void k_scan2(const float* __restrict__ P, const float* __restrict__ S,
                        float* __restrict__ Hin){
  int t = blockIdx.x * 256 + threadIdx.x;      // 0..TL_-1
  float h = 0.f;
  for (int c = 0; c < CH_; c++){
    Hin[(long)c * TL_ + t] = h;
    h = P[(long)c * TL_ + t] * h + S[(long)c * TL_ + t];
  }
}

__global__ void __launch_bounds__(64) k_scan3(
    const float* __restrict__ xd2, const float* __restrict__ u_t,
    const float* __restrict__ Alog, const float* __restrict__ dtw,
    const float* __restrict__ dtb, const float* __restrict__ Dsk,
    const float* __restrict__ Hin, float* __restrict__ ycl){
  int bid = blockIdx.x;
  int chunk = bid & (CH_ - 1); bid >>= 5;
  int dg = bid % 12; bid /= 12;
  int k = bid & 3, b = bid >> 2;
  int lane = threadIdx.x;
  int dgrp = lane >> 2, nsub = lane & 3;
  int d = dg * 16 + dgrp;
  int n0 = nsub * 4;
  int kd = k * 192 + d;
  float Av0 = -__expf(Alog[kd * 16 + n0 + 0]);
  float Av1 = -__expf(Alog[kd * 16 + n0 + 1]);
  float Av2 = -__expf(Alog[kd * 16 + n0 + 2]);
  float Av3 = -__expf(Alog[kd * 16 + n0 + 3]);
  float w0 = dtw[kd*6+0], w1 = dtw[kd*6+1], w2 = dtw[kd*6+2];
  float w3 = dtw[kd*6+3], w4 = dtw[kd*6+4], w5 = dtw[kd*6+5];
  float bias = dtb[kd];
  float Dv = Dsk[kd];
  const float* xrow = xd2 + (long)(b * K_ + k) * L_ * RW_;
  const float* ub = u_t + (long)b * L_ * 192 + d;
  float* yb = ycl + (long)b * L_ * 192;
  long t = (long)((b * K_ + k) * 192 + d) * 16 + n0;
  float4 hv = *(const float4*)&Hin[(long)chunk * TL_ + t];
  float h0 = hv.x, h1 = hv.y, h2 = hv.z, h3 = hv.w;
  int l0 = chunk * CL_;
  for (int l = l0; l < l0 + CL_; l++){
    const float* rp = xrow + (long)l * RW_;
    float4 ra = *(const float4*)(rp + 32);
    float2 rb = *(const float2*)(rp + 36);
    float4 bn = *(const float4*)(rp + n0);
    float4 cn = *(const float4*)(rp + 16 + n0);
    float dlt = softplus_fast(bias + w0*ra.x + w1*ra.y + w2*ra.z + w3*ra.w + w4*rb.x + w5*rb.y);
    int idx = dir_idx(k, l);
    float uv = ub[(long)idx * 192];
    float du = dlt * uv;
    float a0 = __expf(dlt * Av0), a1 = __expf(dlt * Av1);
    float a2 = __expf(dlt * Av2), a3 = __expf(dlt * Av3);
    h0 = a0*h0 + du*bn.x; h1 = a1*h1 + du*bn.y;
    h2 = a2*h2 + du*bn.z; h3 = a3*h3 + du*bn.w;
    float pr = h0*cn.x + h1*cn.y + h2*cn.z + h3*cn.w;
    pr += __shfl_xor(pr, 1, 4);
    pr += __shfl_xor(pr, 2, 4);
    if (nsub == 0) atomicAdd(&yb[(long)idx * 192 + d], pr + Dv * uv);
  }
}

// ---------- out_norm (LN over 192) * silu(z), in-place on ycl ----------
__global__ void k_outnorm(float* __restrict__ y, const float* __restrict__ xz,
                          const float* __restrict__ g, const float* __restrict__ bb){
  int wave = threadIdx.x >> 6, lane = threadIdx.x & 63;
  long p = (long)blockIdx.x * 4 + wave;
  float* row = y + p * 192;
  float v0 = row[lane], v1 = row[lane + 64], v2 = row[lane + 128];
  float s  = wave_sum(v0 + v1 + v2);
  float sq = wave_sum(v0*v0 + v1*v1 + v2*v2);
  float mean = s * (1.0f / 192.0f);
  float var  = sq * (1.0f / 192.0f) - mean * mean;
  float rs = rsqrtf(var + 1e-5f);
  const float* zr = xz + p * 384 + 192;
  row[lane]       = ((v0 - mean) * rs * g[lane]       + bb[lane])       * siluf(zr[lane]);
  row[lane + 64]  = ((v1 - mean) * rs * g[lane + 64]  + bb[lane + 64])  * siluf(zr[lane + 64]);
  row[lane + 128] = ((v2 - mean) * rs * g[lane + 128] + bb[lane + 128]) * siluf(zr[lane + 128]);
}

// ---------- out_proj (192->96) + skip1 ----------
__global__ void k_outproj(const float* __restrict__ y, const float* __restrict__ wt,
                          const float* __restrict__ xf, const float* __restrict__ skip,
                          float* __restrict__ xc){
  __shared__ float yb[384];
  long p0 = (long)blockIdx.x * 2;
  int t = threadIdx.x;                  // 0..191
  yb[t]       = y[p0 * 192 + t];
  yb[t + 192] = y[(p0 + 1) * 192 + t];
  __syncthreads();
  int pp = t / 96, c = t % 96;
  long p = p0 + pp;
  float acc = 0.f;
  #pragma unroll 8
  for (int d = 0; d < 192; d++) acc += yb[pp * 192 + d] * wt[d * 96 + c];
  xc[p * 96 + c] = xf[p * 96 + c] * skip[c] + acc;
}

// ---------- CAB conv1 3x3 96->32 + exact gelu (weights [tap][ci][o]) ----------
__global__ void k_cab1(const float* __restrict__ in, const float* __restrict__ w1t,
                       const float* __restrict__ b1, float* __restrict__ t1){
  int t = threadIdx.x;
  int o = t & 31, pl = t >> 5;
  long pix = (long)blockIdx.x * 8 + pl;
  int b = (int)(pix >> 12); int l = (int)(pix & 4095);
  int hh = l >> 6, ww = l & 63;
  float acc = b1[o];
  for (int dh = -1; dh <= 1; dh++){
    int h2 = hh + dh; if (h2 < 0 || h2 >= 64) continue;
    for (int dw = -1; dw <= 1; dw++){
      int w2 = ww + dw; if (w2 < 0 || w2 >= 64) continue;
      const float* ir = in + ((long)b * L_ + h2 * 64 + w2) * 96;
      const float* wr = w1t + (long)((dh + 1) * 3 + (dw + 1)) * 96 * 32 + o;
      #pragma unroll 8
      for (int ci = 0; ci < 96; ci++) acc += ir[ci] * wr[ci * 32];
    }
  }
  t1[pix * 32 + o] = 0.5f * acc * (1.0f + erff(acc * 0.70710678118654752f));
}

// ---------- CAB conv2 3x3 32->96 (weights [tap][ci][o]) ----------
__global__ void k_cab2(const float* __restrict__ t1, const float* __restrict__ w2t,
                       const float* __restrict__ b2, float* __restrict__ yc){
  int t = threadIdx.x;
  int o = t % 96, pl = t / 96;
  long pix = (long)blockIdx.x * 2 + pl;
  int b = (int)(pix >> 12); int l = (int)(pix & 4095);
  int hh = l >> 6, ww = l & 63;
  float acc = b2[o];
  for (int dh = -1; dh <= 1; dh++){
    int h2 = hh + dh; if (h2 < 0 || h2 >= 64) continue;
    for (int dw = -1; dw <= 1; dw++){
      int w2i = ww + dw; if (w2i < 0 || w2i >= 64) continue;
      const float* ir = t1 + ((long)b * L_ + h2 * 64 + w2i) * 32;
      const float* wr = w2t + (long)((dh + 1) * 3 + (dw + 1)) * 32 * 96 + o;
      #pragma unroll
      for (int ci = 0; ci < 32; ci++) acc += ir[ci] * wr[ci * 96];
    }
  }
  yc[pix * 96 + o] = acc;
}

// ---------- channel-attention ----------
__global__ void k_meanpart(const float* __restrict__ yc, float* __restrict__ part){
  int b = blockIdx.x >> 5, ch = blockIdx.x & 31;
  int o = threadIdx.x;
  float acc = 0.f;
  const float* base = yc + ((long)b * L_ + ch * 128) * 96 + o;
  for (int r = 0; r < 128; r++) acc += base[(long)r * 96];
  part[(long)blockIdx.x * 96 + o] = acc;
}
__global__ void k_attn(const float* __restrict__ part, const float* __restrict__ dw,
                       const float* __restrict__ db, const float* __restrict__ uw,
                       const float* __restrict__ ub, float* __restrict__ a){
  __shared__ float pv[96];
  __shared__ float tv[3];
  int b = blockIdx.x, o = threadIdx.x;
  float acc = 0.f;
  for (int ch = 0; ch < 32; ch++) acc += part[(long)(b * 32 + ch) * 96 + o];
  pv[o] = acc * (1.0f / 4096.0f);
  __syncthreads();
  if (o < 3){
    float t = db[o];
    for (int i2 = 0; i2 < 96; i2++) t += pv[i2] * dw[o * 96 + i2];
    tv[o] = t > 0.f ? t : 0.f;
  }
  __syncthreads();
  float av = ub[o] + tv[0] * uw[o * 3 + 0] + tv[1] * uw[o * 3 + 1] + tv[2] * uw[o * 3 + 2];
  a[b * 96 + o] = 1.0f / (1.0f + __expf(-av));
}

// ---------- final mix ----------
__global__ void k_mix(const float* __restrict__ xc, const float* __restrict__ yc,
                      const float* __restrict__ a, const float* __restrict__ skip2,
                      float* __restrict__ xf){
  long i = (long)blockIdx.x * 256 + threadIdx.x;
  int c = (int)(i % 96); long p = i / 96; int b = (int)(p >> 12);
  xf[i] = xc[i] * skip2[c] + yc[i] * a[b * 96 + c];
}

extern "C" void kernel_launch(void* const* d_in, const int* in_sizes, int n_in,
                              void* d_out, int out_size, void* d_ws, size_t ws_size,
                              hipStream_t stream){
  const float* x          = (const float*)d_in[0];
  const float* ln1_g      = (const float*)d_in[1];
  const float* ln1_b      = (const float*)d_in[2];
  const float* in_proj_w  = (const float*)d_in[3];
  const float* conv_w     = (const float*)d_in[4];
  const float* conv_b     = (const float*)d_in[5];
  const float* x_proj_w   = (const float*)d_in[6];
  const float* dt_proj_w  = (const float*)d_in[7];
  const float* dt_proj_b  = (const float*)d_in[8];
  const float* A_logs     = (const float*)d_in[9];
  const float* Ds         = (const float*)d_in[10];
  const float* out_norm_g = (const float*)d_in[11];
  const float* out_norm_b = (const float*)d_in[12];
  const float* out_proj_w = (const float*)d_in[13];
  const float* skip1      = (const float*)d_in[14];
  const float* ln2_g      = (const float*)d_in[15];
  const float* ln2_b      = (const float*)d_in[16];
  const float* cab1_w     = (const float*)d_in[17];
  const float* cab1_b     = (const float*)d_in[18];
  const float* cab2_w     = (const float*)d_in[19];
  const float* cab2_b     = (const float*)d_in[20];
  const float* ca_dw      = (const float*)d_in[21];
  const float* ca_db      = (const float*)d_in[22];
  const float* ca_uw      = (const float*)d_in[23];
  const float* ca_ub      = (const float*)d_in[24];
  const float* skip2      = (const float*)d_in[25];

  float* W = (float*)d_ws;
  float* xf   = W + 0;         // 786432   (B,L,C)
  float* hb   = W + 786432;    // 786432   ln out  [P overlay during scan]
  float* xz   = W + 1572864;   // 3145728  (B,L,384)
  float* u_t  = W + 4718592;   // 1572864  (B,L,Di) conv+silu, channel-last
  float* xd2  = W + 6291456;   // 1310720  (B,K,L,RW_)
  float* ycl  = W + 7602176;   // 1572864  (B,L,Di)
  float* xc   = W + 9175040;   // 786432   [Hin overlay during scan]
  float* ycab = W + 9961472;   // 786432   [S overlay during scan]
  float* wti  = W + 10747904;  // 36864
  float* wto  = W + 10784768;  // 18432
  float* wt1  = W + 10803200;  // 27648
  float* wt2  = W + 10830848;  // 27648
  float* cwt  = W + 10858496;  // 1728     dw-conv weights [tap][192]
  // aliases into u_t's region (dead during CAB phase):
  float* t1   = u_t;                 // 262144 (B,L,32)
  float* part = u_t + 262144;        // 6144
  float* abuf = u_t + 268288;        // 192
  // scan chunk-state overlays (CH_*TL_ = 786432 each):
  float* P   = hb;
  float* S   = ycab;
  float* Hin = xc;

  k_nchw2nhwc<<<dim3(3072), dim3(256), 0, stream>>>(x, xf);

  for (int i = 0; i < 2; i++){
    const float* ipw  = in_proj_w  + (long)i * 384 * 96;
    const float* opw  = out_proj_w + (long)i * 96 * 192;
    const float* cw   = conv_w     + (long)i * 192 * 9;
    const float* cb   = conv_b     + (long)i * 192;
    const float* xpw  = x_proj_w   + (long)i * 4 * 38 * 192;
    const float* dtw  = dt_proj_w  + (long)i * 4 * 192 * 6;
    const float* dtbp = dt_proj_b  + (long)i * 4 * 192;
    const float* alog = A_logs     + (long)i * 768 * 16;
    const float* dsp  = Ds         + (long)i * 768;

    k_transpose<<<dim3(144), dim3(256), 0, stream>>>(ipw, wti, 384, 96);
    k_transpose<<<dim3(72),  dim3(256), 0, stream>>>(opw, wto, 96, 192);
    k_wconv_t<<<dim3(108), dim3(256), 0, stream>>>(cab1_w + (long)i*32*96*9, wt1, 32, 96);
    k_wconv_t<<<dim3(108), dim3(256), 0, stream>>>(cab2_w + (long)i*96*32*9, wt2, 96, 32);
    k_wconv_t<<<dim3(7),   dim3(256), 0, stream>>>(cw, cwt, 192, 1);

    k_ln96<<<dim3(2048), dim3(256), 0, stream>>>(xf, hb, ln1_g + i*96, ln1_b + i*96);
    k_inproj<<<dim3(8192), dim3(384), 0, stream>>>(hb, wti, xz);
    k_dwconv<<<dim3(2048, 2), dim3(384), 0, stream>>>(xz, cwt, cb, u_t);
    k_xdbl<<<dim3(64, 8), dim3(256), 0, stream>>>(u_t, xpw, xd2);

    // chunked scan: pass1 -> (P,S), pass2 -> Hin, memset y, pass3 -> y
    k_scan1<<<dim3(3072), dim3(64), 0, stream>>>(xd2, u_t, alog, dtw, dtbp, P, S);
    k_scan2<<<dim3(96), dim3(256), 0, stream>>>(P, S, Hin);
    hipMemsetAsync(ycl, 0, (size_t)1572864 * sizeof(float), stream);
    k_scan3<<<dim3(3072), dim3(64), 0, stream>>>(xd2, u_t, alog, dtw, dtbp, dsp, Hin, ycl);

    k_outnorm<<<dim3(2048), dim3(256), 0, stream>>>(ycl, xz, out_norm_g + i*192, out_norm_b + i*192);
    k_outproj<<<dim3(4096), dim3(192), 0, stream>>>(ycl, wto, xf, skip1 + i*96, xc);

    k_ln96<<<dim3(2048), dim3(256), 0, stream>>>(xc, hb, ln2_g + i*96, ln2_b + i*96);
    k_cab1<<<dim3(1024), dim3(256), 0, stream>>>(hb, wt1, cab1_b + i*32, t1);
    k_cab2<<<dim3(4096), dim3(192), 0, stream>>>(t1, wt2, cab2_b + i*96, ycab);
    k_meanpart<<<dim3(64), dim3(96), 0, stream>>>(ycab, part);
    k_attn<<<dim3(2), dim3(96), 0, stream>>>(part, ca_dw + i*288, ca_db + i*3,
                                             ca_uw + i*288, ca_ub + i*96, abuf);
    k_mix<<<dim3(3072), dim3(256), 0, stream>>>(xc, ycab, abuf, skip2 + i*96, xf);
  }

  k_nhwc2nchw<<<dim3(3072), dim3(256), 0, stream>>>(xf, (float*)d_out);
}

// Round 5
// 888.831 us; speedup vs baseline: 8.9894x; 1.1719x over previous
//
#include <hip/hip_runtime.h>
#include <math.h>

// Problem constants (fixed by the reference)
constexpr int B_  = 2;
constexpr int L_  = 4096;   // H*W
constexpr int Di_ = 192;    // D_INNER
constexpr int K_  = 4;      // directions
constexpr int CH_ = 32;     // scan chunks
constexpr int CL_ = 128;    // chunk length (CH_*CL_ == L_)
constexpr int TL_ = 24576;  // total state lanes = B*K*Di*N
constexpr int RW_ = 40;     // xd row stride: [B(16) | C(16) | dt(6) | pad(2)]
constexpr int PSZ_ = 112320; // per-layer prepped-weight floats

__device__ __forceinline__ float siluf(float x){ return x / (1.0f + __expf(-x)); }
__device__ __forceinline__ float softplus_fast(float x){
  return x > 15.0f ? x : __logf(1.0f + __expf(x));
}
__device__ __forceinline__ float wave_sum(float v){
  #pragma unroll
  for (int off = 32; off > 0; off >>= 1) v += __shfl_xor(v, off, 64);
  return v;
}
// direction index maps: scan position l -> row-major spatial index
__device__ __forceinline__ int dir_idx(int k, int l){
  if (k == 0) return l;
  if (k == 1) return ((l & 63) << 6) | (l >> 6);
  if (k == 2) return (L_ - 1) - l;
  int lm = (L_ - 1) - l; return ((lm & 63) << 6) | (lm >> 6);
}

// ---------- layout shufflers ----------
__global__ void k_nchw2nhwc(const float* __restrict__ x, float* __restrict__ xf){
  long i = (long)blockIdx.x * 256 + threadIdx.x;
  int c = (int)(i % 96); long p = i / 96; int b = (int)(p >> 12); int l = (int)(p & 4095);
  xf[i] = x[((long)b * 96 + c) * L_ + l];
}
__global__ void k_nhwc2nchw(const float* __restrict__ xf, float* __restrict__ out){
  long i = (long)blockIdx.x * 256 + threadIdx.x;
  int l = (int)(i & 4095); long q = i >> 12; int c = (int)(q % 96); int b = (int)(q / 96);
  out[i] = xf[((long)b * L_ + l) * 96 + c];
}

// ---------- single prep kernel: all weight transforms, both layers ----------
__global__ void k_prep(const float* __restrict__ ipw, const float* __restrict__ opw,
                       const float* __restrict__ c1w, const float* __restrict__ c2w,
                       const float* __restrict__ cw,
                       float* __restrict__ wti, float* __restrict__ wto,
                       float* __restrict__ wt1, float* __restrict__ wt2,
                       float* __restrict__ cwt){
  int t = blockIdx.x * 256 + threadIdx.x;
  if (t >= 2 * PSZ_) return;
  int i = t / PSZ_, r = t % PSZ_;
  if (r < 36864){
    int rr = r / 96, c = r % 96;
    wti[i*36864 + c*384 + rr] = ipw[(long)i*36864 + r];
  } else if ((r -= 36864) < 18432){
    int c = r / 192, d = r % 192;
    wto[i*18432 + d*96 + c] = opw[(long)i*18432 + r];
  } else if ((r -= 18432) < 27648){
    int tap = r % 9; int rem = r / 9; int ci = rem % 96; int o = rem / 96;
    wt1[i*27648 + (tap*96+ci)*32 + o] = c1w[(long)i*27648 + r];
  } else if ((r -= 27648) < 27648){
    int tap = r % 9; int rem = r / 9; int ci = rem % 32; int o = rem / 32;
    wt2[i*27648 + (tap*32+ci)*96 + o] = c2w[(long)i*27648 + r];
  } else {
    r -= 27648;
    int d = r / 9, tap = r % 9;
    cwt[i*1728 + tap*192 + d] = cw[(long)i*1728 + r];
  }
}

// ---------- layernorm over 96 channels (wave per pixel) ----------
__global__ void k_ln96(const float* __restrict__ in, float* __restrict__ out,
                       const float* __restrict__ g, const float* __restrict__ bb){
  int wave = threadIdx.x >> 6, lane = threadIdx.x & 63;
  long p = (long)blockIdx.x * 4 + wave;
  const float* row = in + p * 96;
  float v0 = row[lane];
  float v1 = (lane < 32) ? row[64 + lane] : 0.0f;
  float s  = wave_sum(v0 + v1);
  float sq = wave_sum(v0 * v0 + v1 * v1);
  float mean = s * (1.0f / 96.0f);
  float var  = sq * (1.0f / 96.0f) - mean * mean;
  float rs = rsqrtf(var + 1e-5f);
  out[p * 96 + lane] = (v0 - mean) * rs * g[lane] + bb[lane];
  if (lane < 32) out[p * 96 + 64 + lane] = (v1 - mean) * rs * g[64 + lane] + bb[64 + lane];
}

// ---------- fused LN1 + in_proj: xf row -> LN -> (96x384) -> xz ----------
__global__ void __launch_bounds__(384) k_infuse(const float* __restrict__ xf,
                                               const float* __restrict__ wti,
                                               const float* __restrict__ g,
                                               const float* __restrict__ bb,
                                               float* __restrict__ xz){
  __shared__ float hb2[96];
  __shared__ float stats[2];
  long p = blockIdx.x;
  int t = threadIdx.x;                 // 0..383
  if (t < 96) hb2[t] = xf[p * 96 + t];
  __syncthreads();
  if (t < 64){
    float v0 = hb2[t];
    float v1 = (t < 32) ? hb2[64 + t] : 0.0f;
    float s  = wave_sum(v0 + v1);
    float sq = wave_sum(v0 * v0 + v1 * v1);
    if (t == 0){
      float mean = s * (1.0f / 96.0f);
      float var  = sq * (1.0f / 96.0f) - mean * mean;
      stats[0] = mean; stats[1] = rsqrtf(var + 1e-5f);
    }
  }
  __syncthreads();
  if (t < 96) hb2[t] = (hb2[t] - stats[0]) * stats[1] * g[t] + bb[t];
  __syncthreads();
  float acc = 0.f;
  #pragma unroll 8
  for (int c = 0; c < 96; c++) acc += hb2[c] * wti[(long)c * 384 + t];
  xz[p * 384 + t] = acc;
}

// ---------- depthwise 3x3 conv + bias + silu -> u_t (B,L,Di) channel-last ----------
__global__ void k_dwconv(const float* __restrict__ xz, const float* __restrict__ cwt,
                         const float* __restrict__ cb, float* __restrict__ u_t){
  int tid = threadIdx.x;               // 0..383  (2 pixels x 192 ch)
  int d = tid % 192, px = tid / 192;
  int l = blockIdx.x * 2 + px;
  int b = blockIdx.y;
  int hh = l >> 6, ww = l & 63;
  float acc = cb[d];
  #pragma unroll
  for (int tap = 0; tap < 9; tap++){
    int dh = tap / 3 - 1, dw = tap % 3 - 1;
    int h2 = hh + dh, w2 = ww + dw;
    if (h2 < 0 || h2 >= 64 || w2 < 0 || w2 >= 64) continue;
    acc += xz[((long)(b * L_ + h2 * 64 + w2)) * 384 + d] * cwt[tap * 192 + d];
  }
  u_t[((long)b * L_ + l) * 192 + d] = siluf(acc);
}

// ---------- x_dbl rows (8 waves, 5 uniform cols/wave, float4 LDS) ----------
__global__ void __launch_bounds__(512) k_xdbl(const float* __restrict__ u_t,
                                              const float* __restrict__ xw,
                                              float* __restrict__ xd2){
  __shared__ __align__(16) float su[64][196];   // stride 196: f4-aligned, conflict-free
  int bk = blockIdx.y; int b = bk >> 2, k = bk & 3;
  int l0 = blockIdx.x * 64;
  int tid = threadIdx.x;               // 0..511
  for (int e = tid; e < 64 * 48; e += 512){
    int r = e / 48, s2 = e - r * 48;
    int idx = dir_idx(k, l0 + r);
    *(float4*)&su[r][s2 * 4] = *(const float4*)&u_t[((long)b * L_ + idx) * 192 + s2 * 4];
  }
  __syncthreads();
  int lane = tid & 63, wv = tid >> 6;  // wv 0..7 wave-uniform
  const float* wb = xw + (long)k * 38 * 192;
  float acc[5] = {0.f, 0.f, 0.f, 0.f, 0.f};
  for (int d = 0; d < 192; d += 4){
    float4 uv = *(const float4*)&su[lane][d];
    #pragma unroll
    for (int j = 0; j < 5; j++){
      int c = 8 * j + wv;
      if (c < 38){
        const float* wp = wb + c * 192 + d;     // wave-uniform -> s_load
        acc[j] += uv.x * wp[0] + uv.y * wp[1] + uv.z * wp[2] + uv.w * wp[3];
      }
    }
  }
  float* rowp = xd2 + ((long)bk * L_ + (l0 + lane)) * RW_;
  #pragma unroll
  for (int j = 0; j < 5; j++){
    int c = 8 * j + wv;
    if (c < 38){
      int pos = (c < 6) ? 32 + c : c - 6;  // dt -> 32..37, B -> 0..15, C -> 16..31
      rowp[pos] = acc[j];
    }
  }
}

// ================= chunked selective scan (wave = 16 d x 4 n, 4 states/lane) ======
__global__ void __launch_bounds__(64) k_scan1(
    const float* __restrict__ xd2, const float* __restrict__ u_t,
    const float* __restrict__ Alog, const float* __restrict__ dtw,
    const float* __restrict__ dtb,
    float* __restrict__ P, float* __restrict__ S){
  int bid = blockIdx.x;
  int chunk = bid & (CH_ - 1); bid >>= 5;
  int dg = bid % 12; bid /= 12;
  int k = bid & 3, b = bid >> 2;
  int lane = threadIdx.x;
  int dgrp = lane >> 2, nsub = lane & 3;
  int d = dg * 16 + dgrp;
  int n0 = nsub * 4;
  int kd = k * 192 + d;
  float Av0 = -__expf(Alog[kd * 16 + n0 + 0]);
  float Av1 = -__expf(Alog[kd * 16 + n0 + 1]);
  float Av2 = -__expf(Alog[kd * 16 + n0 + 2]);
  float Av3 = -__expf(Alog[kd * 16 + n0 + 3]);
  float w0 = dtw[kd*6+0], w1 = dtw[kd*6+1], w2 = dtw[kd*6+2];
  float w3 = dtw[kd*6+3], w4 = dtw[kd*6+4], w5 = dtw[kd*6+5];
  float bias = dtb[kd];
  const float* xrow = xd2 + (long)(b * K_ + k) * L_ * RW_;
  const float* ub = u_t + (long)b * L_ * 192 + d;
  float h0=0,h1=0,h2=0,h3=0, p0=1,p1=1,p2=1,p3=1;
  int l0 = chunk * CL_;
  for (int l = l0; l < l0 + CL_; l++){
    const float* rp = xrow + (long)l * RW_;
    float4 ra = *(const float4*)(rp + 32);
    float2 rb = *(const float2*)(rp + 36);
    float4 bn = *(const float4*)(rp + n0);
    float dlt = softplus_fast(bias + w0*ra.x + w1*ra.y + w2*ra.z + w3*ra.w + w4*rb.x + w5*rb.y);
    float uv = ub[(long)dir_idx(k, l) * 192];
    float du = dlt * uv;
    float a0 = __expf(dlt * Av0), a1 = __expf(dlt * Av1);
    float a2 = __expf(dlt * Av2), a3 = __expf(dlt * Av3);
    h0 = a0*h0 + du*bn.x; h1 = a1*h1 + du*bn.y;
    h2 = a2*h2 + du*bn.z; h3 = a3*h3 + du*bn.w;
    p0 *= a0; p1 *= a1; p2 *= a2; p3 *= a3;
  }
  long t = (long)((b * K_ + k) * 192 + d) * 16 + n0;
  *(float4*)&P[(long)chunk * TL_ + t] = make_float4(p0, p1, p2, p3);
  *(float4*)&S[(long)chunk * TL_ + t] = make_float4(h0, h1, h2, h3);
}

__global__ void k_scan2(const float* __restrict__ P, const float* __restrict__ S,
                        float* __restrict__ Hin){
  int t = blockIdx.x * 256 + threadIdx.x;      // 0..TL_-1
  float h = 0.f;
  for (int c = 0; c < CH_; c++){
    Hin[(long)c * TL_ + t] = h;
    h = P[(long)c * TL_ + t] * h + S[(long)c * TL_ + t];
  }
}

__global__ void __launch_bounds__(64) k_scan3(
    const float* __restrict__ xd2, const float* __restrict__ u_t,
    const float* __restrict__ Alog, const float* __restrict__ dtw,
    const float* __restrict__ dtb, const float* __restrict__ Dsk,
    const float* __restrict__ Hin, float* __restrict__ ycl){
  int bid = blockIdx.x;
  int chunk = bid & (CH_ - 1); bid >>= 5;
  int dg = bid % 12; bid /= 12;
  int k = bid & 3, b = bid >> 2;
  int lane = threadIdx.x;
  int dgrp = lane >> 2, nsub = lane & 3;
  int d = dg * 16 + dgrp;
  int n0 = nsub * 4;
  int kd = k * 192 + d;
  float Av0 = -__expf(Alog[kd * 16 + n0 + 0]);
  float Av1 = -__expf(Alog[kd * 16 + n0 + 1]);
  float Av2 = -__expf(Alog[kd * 16 + n0 + 2]);
  float Av3 = -__expf(Alog[kd * 16 + n0 + 3]);
  float w0 = dtw[kd*6+0], w1 = dtw[kd*6+1], w2 = dtw[kd*6+2];
  float w3 = dtw[kd*6+3], w4 = dtw[kd*6+4], w5 = dtw[kd*6+5];
  float bias = dtb[kd];
  float Dv = Dsk[kd];
  const float* xrow = xd2 + (long)(b * K_ + k) * L_ * RW_;
  const float* ub = u_t + (long)b * L_ * 192 + d;
  float* yb = ycl + (long)b * L_ * 192;
  long t = (long)((b * K_ + k) * 192 + d) * 16 + n0;
  float4 hv = *(const float4*)&Hin[(long)chunk * TL_ + t];
  float h0 = hv.x, h1 = hv.y, h2 = hv.z, h3 = hv.w;
  int l0 = chunk * CL_;
  for (int l = l0; l < l0 + CL_; l++){
    const float* rp = xrow + (long)l * RW_;
    float4 ra = *(const float4*)(rp + 32);
    float2 rb = *(const float2*)(rp + 36);
    float4 bn = *(const float4*)(rp + n0);
    float4 cn = *(const float4*)(rp + 16 + n0);
    float dlt = softplus_fast(bias + w0*ra.x + w1*ra.y + w2*ra.z + w3*ra.w + w4*rb.x + w5*rb.y);
    int idx = dir_idx(k, l);
    float uv = ub[(long)idx * 192];
    float du = dlt * uv;
    float a0 = __expf(dlt * Av0), a1 = __expf(dlt * Av1);
    float a2 = __expf(dlt * Av2), a3 = __expf(dlt * Av3);
    h0 = a0*h0 + du*bn.x; h1 = a1*h1 + du*bn.y;
    h2 = a2*h2 + du*bn.z; h3 = a3*h3 + du*bn.w;
    float pr = h0*cn.x + h1*cn.y + h2*cn.z + h3*cn.w;
    pr += __shfl_xor(pr, 1, 4);
    pr += __shfl_xor(pr, 2, 4);
    if (nsub == 0) atomicAdd(&yb[(long)idx * 192 + d], pr + Dv * uv);
  }
}

// ---------- fused out_norm (LN 192) * silu(z) + out_proj + skip1 ----------
__global__ void __launch_bounds__(384) k_outfuse(const float* __restrict__ ycl,
                                                const float* __restrict__ xz,
                                                const float* __restrict__ g,
                                                const float* __restrict__ bb,
                                                const float* __restrict__ wt,
                                                const float* __restrict__ xf,
                                                const float* __restrict__ skip,
                                                float* __restrict__ xc){
  __shared__ float yb[2][192];
  __shared__ float red[6][2];
  __shared__ float st[2][2];
  long p0 = (long)blockIdx.x * 2;
  int t = threadIdx.x;                 // 0..383
  int pp = t / 192, e = t % 192;
  int wv = t >> 6;                     // 0..5 (waves 0-2 -> pp0, 3-5 -> pp1)
  long p = p0 + pp;
  float v = ycl[p * 192 + e];
  float s  = wave_sum(v);
  float sq = wave_sum(v * v);
  if ((t & 63) == 0){ red[wv][0] = s; red[wv][1] = sq; }
  __syncthreads();
  if (t < 2){
    float ss = red[t*3][0] + red[t*3+1][0] + red[t*3+2][0];
    float qq = red[t*3][1] + red[t*3+1][1] + red[t*3+2][1];
    float mean = ss * (1.0f / 192.0f);
    float var  = qq * (1.0f / 192.0f) - mean * mean;
    st[t][0] = mean; st[t][1] = rsqrtf(var + 1e-5f);
  }
  __syncthreads();
  float zz = xz[p * 384 + 192 + e];
  yb[pp][e] = ((v - st[pp][0]) * st[pp][1] * g[e] + bb[e]) * siluf(zz);
  __syncthreads();
  if (t < 192){
    int pp2 = t / 96, c = t % 96;
    float acc = 0.f;
    #pragma unroll 8
    for (int d = 0; d < 192; d++) acc += yb[pp2][d] * wt[d * 96 + c];
    long pq = p0 + pp2;
    xc[pq * 96 + c] = xf[pq * 96 + c] * skip[c] + acc;
  }
}

// ---------- CAB conv1 3x3 96->32 + exact gelu (weights [tap][ci][o]) ----------
__global__ void k_cab1(const float* __restrict__ in, const float* __restrict__ w1t,
                       const float* __restrict__ b1, float* __restrict__ t1){
  int t = threadIdx.x;
  int o = t & 31, pl = t >> 5;
  long pix = (long)blockIdx.x * 8 + pl;
  int b = (int)(pix >> 12); int l = (int)(pix & 4095);
  int hh = l >> 6, ww = l & 63;
  float acc = b1[o];
  for (int dh = -1; dh <= 1; dh++){
    int h2 = hh + dh; if (h2 < 0 || h2 >= 64) continue;
    for (int dw = -1; dw <= 1; dw++){
      int w2 = ww + dw; if (w2 < 0 || w2 >= 64) continue;
      const float* ir = in + ((long)b * L_ + h2 * 64 + w2) * 96;
      const float* wr = w1t + (long)((dh + 1) * 3 + (dw + 1)) * 96 * 32 + o;
      #pragma unroll
      for (int ci = 0; ci < 96; ci += 4){
        float4 iv = *(const float4*)&ir[ci];
        acc += iv.x * wr[ci*32] + iv.y * wr[(ci+1)*32]
             + iv.z * wr[(ci+2)*32] + iv.w * wr[(ci+3)*32];
      }
    }
  }
  t1[pix * 32 + o] = 0.5f * acc * (1.0f + erff(acc * 0.70710678118654752f));
}

// ---------- CAB conv2 3x3 32->96 (weights [tap][ci][o]) ----------
__global__ void k_cab2(const float* __restrict__ t1, const float* __restrict__ w2t,
                       const float* __restrict__ b2, float* __restrict__ yc){
  int t = threadIdx.x;
  int o = t % 96, pl = t / 96;
  long pix = (long)blockIdx.x * 2 + pl;
  int b = (int)(pix >> 12); int l = (int)(pix & 4095);
  int hh = l >> 6, ww = l & 63;
  float acc = b2[o];
  for (int dh = -1; dh <= 1; dh++){
    int h2 = hh + dh; if (h2 < 0 || h2 >= 64) continue;
    for (int dw = -1; dw <= 1; dw++){
      int w2i = ww + dw; if (w2i < 0 || w2i >= 64) continue;
      const float* ir = t1 + ((long)b * L_ + h2 * 64 + w2i) * 32;
      const float* wr = w2t + (long)((dh + 1) * 3 + (dw + 1)) * 32 * 96 + o;
      #pragma unroll
      for (int ci = 0; ci < 32; ci += 4){
        float4 iv = *(const float4*)&ir[ci];
        acc += iv.x * wr[ci*96] + iv.y * wr[(ci+1)*96]
             + iv.z * wr[(ci+2)*96] + iv.w * wr[(ci+3)*96];
      }
    }
  }
  yc[pix * 96 + o] = acc;
}

// ---------- channel-attention ----------
__global__ void k_meanpart(const float* __restrict__ yc, float* __restrict__ part){
  int b = blockIdx.x >> 5, ch = blockIdx.x & 31;
  int o = threadIdx.x;
  float acc = 0.f;
  const float* base = yc + ((long)b * L_ + ch * 128) * 96 + o;
  for (int r = 0; r < 128; r++) acc += base[(long)r * 96];
  part[(long)blockIdx.x * 96 + o] = acc;
}
__global__ void k_attn(const float* __restrict__ part, const float* __restrict__ dw,
                       const float* __restrict__ db, const float* __restrict__ uw,
                       const float* __restrict__ ub, float* __restrict__ a){
  __shared__ float pv[96];
  __shared__ float tv[3];
  int b = blockIdx.x, o = threadIdx.x;
  float acc = 0.f;
  for (int ch = 0; ch < 32; ch++) acc += part[(long)(b * 32 + ch) * 96 + o];
  pv[o] = acc * (1.0f / 4096.0f);
  __syncthreads();
  if (o < 3){
    float t = db[o];
    for (int i2 = 0; i2 < 96; i2++) t += pv[i2] * dw[o * 96 + i2];
    tv[o] = t > 0.f ? t : 0.f;
  }
  __syncthreads();
  float av = ub[o] + tv[0] * uw[o * 3 + 0] + tv[1] * uw[o * 3 + 1] + tv[2] * uw[o * 3 + 2];
  a[b * 96 + o] = 1.0f / (1.0f + __expf(-av));
}

// ---------- final mix ----------
__global__ void k_mix(const float* __restrict__ xc, const float* __restrict__ yc,
                      const float* __restrict__ a, const float* __restrict__ skip2,
                      float* __restrict__ xf){
  long i = (long)blockIdx.x * 256 + threadIdx.x;
  int c = (int)(i % 96); long p = i / 96; int b = (int)(p >> 12);
  xf[i] = xc[i] * skip2[c] + yc[i] * a[b * 96 + c];
}

extern "C" void kernel_launch(void* const* d_in, const int* in_sizes, int n_in,
                              void* d_out, int out_size, void* d_ws, size_t ws_size,
                              hipStream_t stream){
  const float* x          = (const float*)d_in[0];
  const float* ln1_g      = (const float*)d_in[1];
  const float* ln1_b      = (const float*)d_in[2];
  const float* in_proj_w  = (const float*)d_in[3];
  const float* conv_w     = (const float*)d_in[4];
  const float* conv_b     = (const float*)d_in[5];
  const float* x_proj_w   = (const float*)d_in[6];
  const float* dt_proj_w  = (const float*)d_in[7];
  const float* dt_proj_b  = (const float*)d_in[8];
  const float* A_logs     = (const float*)d_in[9];
  const float* Ds         = (const float*)d_in[10];
  const float* out_norm_g = (const float*)d_in[11];
  const float* out_norm_b = (const float*)d_in[12];
  const float* out_proj_w = (const float*)d_in[13];
  const float* skip1      = (const float*)d_in[14];
  const float* ln2_g      = (const float*)d_in[15];
  const float* ln2_b      = (const float*)d_in[16];
  const float* cab1_w     = (const float*)d_in[17];
  const float* cab1_b     = (const float*)d_in[18];
  const float* cab2_w     = (const float*)d_in[19];
  const float* cab2_b     = (const float*)d_in[20];
  const float* ca_dw      = (const float*)d_in[21];
  const float* ca_db      = (const float*)d_in[22];
  const float* ca_uw      = (const float*)d_in[23];
  const float* ca_ub      = (const float*)d_in[24];
  const float* skip2      = (const float*)d_in[25];

  float* W = (float*)d_ws;
  float* xf   = W + 0;         // 786432   (B,L,C)
  float* hb   = W + 786432;    // 786432   ln2 out  [P overlay during scan]
  float* xz   = W + 1572864;   // 3145728  (B,L,384)
  float* u_t  = W + 4718592;   // 1572864  (B,L,Di) conv+silu, channel-last
  float* xd2  = W + 6291456;   // 1310720  (B,K,L,RW_)
  float* ycl  = W + 7602176;   // 1572864  (B,L,Di)
  float* xc   = W + 9175040;   // 786432   [Hin overlay during scan]
  float* ycab = W + 9961472;   // 786432   [S overlay during scan]
  float* wti2 = W + 10747904;  // 2x36864
  float* wto2 = W + 10821632;  // 2x18432
  float* wt12 = W + 10858496;  // 2x27648
  float* wt22 = W + 10913792;  // 2x27648
  float* cwt2 = W + 10969088;  // 2x1728   -> end 10972544 (43.9 MB)
  // aliases into u_t's region (dead during CAB phase):
  float* t1   = u_t;                 // 262144 (B,L,32)
  float* part = u_t + 262144;        // 6144
  float* abuf = u_t + 268288;        // 192
  // scan chunk-state overlays (CH_*TL_ = 786432 each):
  float* P   = hb;
  float* S   = ycab;
  float* Hin = xc;

  k_nchw2nhwc<<<dim3(3072), dim3(256), 0, stream>>>(x, xf);
  k_prep<<<dim3((2*PSZ_ + 255)/256), dim3(256), 0, stream>>>(
      in_proj_w, out_proj_w, cab1_w, cab2_w, conv_w, wti2, wto2, wt12, wt22, cwt2);

  for (int i = 0; i < 2; i++){
    const float* xpw  = x_proj_w   + (long)i * 4 * 38 * 192;
    const float* dtw  = dt_proj_w  + (long)i * 4 * 192 * 6;
    const float* dtbp = dt_proj_b  + (long)i * 4 * 192;
    const float* alog = A_logs     + (long)i * 768 * 16;
    const float* dsp  = Ds         + (long)i * 768;
    const float* wti = wti2 + i * 36864;
    const float* wto = wto2 + i * 18432;
    const float* wt1 = wt12 + i * 27648;
    const float* wt2 = wt22 + i * 27648;
    const float* cwt = cwt2 + i * 1728;

    k_infuse<<<dim3(8192), dim3(384), 0, stream>>>(xf, wti, ln1_g + i*96, ln1_b + i*96, xz);
    k_dwconv<<<dim3(2048, 2), dim3(384), 0, stream>>>(xz, cwt, conv_b + i*192, u_t);
    k_xdbl<<<dim3(64, 8), dim3(512), 0, stream>>>(u_t, xpw, xd2);

    // chunked scan: pass1 -> (P,S), pass2 -> Hin, memset y, pass3 -> y
    k_scan1<<<dim3(3072), dim3(64), 0, stream>>>(xd2, u_t, alog, dtw, dtbp, P, S);
    k_scan2<<<dim3(96), dim3(256), 0, stream>>>(P, S, Hin);
    hipMemsetAsync(ycl, 0, (size_t)1572864 * sizeof(float), stream);
    k_scan3<<<dim3(3072), dim3(64), 0, stream>>>(xd2, u_t, alog, dtw, dtbp, dsp, Hin, ycl);

    k_outfuse<<<dim3(4096), dim3(384), 0, stream>>>(ycl, xz, out_norm_g + i*192,
                                                    out_norm_b + i*192, wto, xf,
                                                    skip1 + i*96, xc);

    k_ln96<<<dim3(2048), dim3(256), 0, stream>>>(xc, hb, ln2_g + i*96, ln2_b + i*96);
    k_cab1<<<dim3(1024), dim3(256), 0, stream>>>(hb, wt1, cab1_b + i*32, t1);
    k_cab2<<<dim3(4096), dim3(192), 0, stream>>>(t1, wt2, cab2_b + i*96, ycab);
    k_meanpart<<<dim3(64), dim3(96), 0, stream>>>(ycab, part);
    k_attn<<<dim3(2), dim3(96), 0, stream>>>(part, ca_dw + i*288, ca_db + i*3,
                                             ca_uw + i*288, ca_ub + i*96, abuf);
    k_mix<<<dim3(3072), dim3(256), 0, stream>>>(xc, ycab, abuf, skip2 + i*96, xf);
  }

  k_nhwc2nchw<<<dim3(3072), dim3(256), 0, stream>>>(xf, (float*)d_out);
}

// Round 6
// 770.197 us; speedup vs baseline: 10.3740x; 1.1540x over previous
//
#include <hip/hip_runtime.h>
#include <math.h>

// Problem constants (fixed by the reference)
constexpr int B_  = 2;
constexpr int L_  = 4096;   // H*W
constexpr int Di_ = 192;    // D_INNER
constexpr int K_  = 4;      // directions
constexpr int CH_ = 64;     // scan chunks
constexpr int CL_ = 64;     // chunk length (CH_*CL_ == L_)
constexpr int TL_ = 24576;  // total state lanes = B*K*Di*N
constexpr int RW_ = 40;     // xd row stride: [B(16) | C(16) | dt(6) | pad(2)]
constexpr int PSZ_ = 112320; // per-layer prepped-weight floats

__device__ __forceinline__ float siluf(float x){ return x / (1.0f + __expf(-x)); }
__device__ __forceinline__ float softplus_fast(float x){
  return x > 15.0f ? x : __logf(1.0f + __expf(x));
}
__device__ __forceinline__ float wave_sum(float v){
  #pragma unroll
  for (int off = 32; off > 0; off >>= 1) v += __shfl_xor(v, off, 64);
  return v;
}
// direction index maps: scan position l -> row-major spatial index
__device__ __forceinline__ int dir_idx(int k, int l){
  if (k == 0) return l;
  if (k == 1) return ((l & 63) << 6) | (l >> 6);
  if (k == 2) return (L_ - 1) - l;
  int lm = (L_ - 1) - l; return ((lm & 63) << 6) | (lm >> 6);
}

// ---------- layout shufflers ----------
__global__ void k_nchw2nhwc(const float* __restrict__ x, float* __restrict__ xf){
  long i = (long)blockIdx.x * 256 + threadIdx.x;
  int c = (int)(i % 96); long p = i / 96; int b = (int)(p >> 12); int l = (int)(p & 4095);
  xf[i] = x[((long)b * 96 + c) * L_ + l];
}
__global__ void k_nhwc2nchw(const float* __restrict__ xf, float* __restrict__ out){
  long i = (long)blockIdx.x * 256 + threadIdx.x;
  int l = (int)(i & 4095); long q = i >> 12; int c = (int)(q % 96); int b = (int)(q / 96);
  out[i] = xf[((long)b * L_ + l) * 96 + c];
}

// ---------- single prep kernel: all weight transforms, both layers ----------
__global__ void k_prep(const float* __restrict__ ipw, const float* __restrict__ opw,
                       const float* __restrict__ c1w, const float* __restrict__ c2w,
                       const float* __restrict__ cw,
                       float* __restrict__ wti, float* __restrict__ wto,
                       float* __restrict__ wt1, float* __restrict__ wt2,
                       float* __restrict__ cwt){
  int t = blockIdx.x * 256 + threadIdx.x;
  if (t >= 2 * PSZ_) return;
  int i = t / PSZ_, r = t % PSZ_;
  if (r < 36864){
    int rr = r / 96, c = r % 96;
    wti[i*36864 + c*384 + rr] = ipw[(long)i*36864 + r];
  } else if ((r -= 36864) < 18432){
    int c = r / 192, d = r % 192;
    wto[i*18432 + d*96 + c] = opw[(long)i*18432 + r];
  } else if ((r -= 18432) < 27648){
    int tap = r % 9; int rem = r / 9; int ci = rem % 96; int o = rem / 96;
    wt1[i*27648 + (tap*96+ci)*32 + o] = c1w[(long)i*27648 + r];
  } else if ((r -= 27648) < 27648){
    int tap = r % 9; int rem = r / 9; int ci = rem % 32; int o = rem / 32;
    wt2[i*27648 + (tap*32+ci)*96 + o] = c2w[(long)i*27648 + r];
  } else {
    r -= 27648;
    int d = r / 9, tap = r % 9;
    cwt[i*1728 + tap*192 + d] = cw[(long)i*1728 + r];
  }
}

// ---------- layernorm over 96 channels (wave per pixel) ----------
__global__ void k_ln96(const float* __restrict__ in, float* __restrict__ out,
                       const float* __restrict__ g, const float* __restrict__ bb){
  int wave = threadIdx.x >> 6, lane = threadIdx.x & 63;
  long p = (long)blockIdx.x * 4 + wave;
  const float* row = in + p * 96;
  float v0 = row[lane];
  float v1 = (lane < 32) ? row[64 + lane] : 0.0f;
  float s  = wave_sum(v0 + v1);
  float sq = wave_sum(v0 * v0 + v1 * v1);
  float mean = s * (1.0f / 96.0f);
  float var  = sq * (1.0f / 96.0f) - mean * mean;
  float rs = rsqrtf(var + 1e-5f);
  out[p * 96 + lane] = (v0 - mean) * rs * g[lane] + bb[lane];
  if (lane < 32) out[p * 96 + 64 + lane] = (v1 - mean) * rs * g[64 + lane] + bb[64 + lane];
}

// ---------- fused LN1 + in_proj, 4 pixels per block ----------
__global__ void __launch_bounds__(384) k_infuse(const float* __restrict__ xf,
                                               const float* __restrict__ wti,
                                               const float* __restrict__ g,
                                               const float* __restrict__ bb,
                                               float* __restrict__ xz){
  __shared__ float hb2[4][96];
  __shared__ float st[4][2];
  long p0 = (long)blockIdx.x * 4;
  int t = threadIdx.x;                 // 0..383
  {
    int pp = t / 96, c = t % 96;
    hb2[pp][c] = xf[(p0 + pp) * 96 + c];
  }
  __syncthreads();
  int wv = t >> 6, lane = t & 63;
  if (wv < 4){
    float v0 = hb2[wv][lane];
    float v1 = (lane < 32) ? hb2[wv][64 + lane] : 0.0f;
    float s  = wave_sum(v0 + v1);
    float sq = wave_sum(v0 * v0 + v1 * v1);
    if (lane == 0){
      float mean = s * (1.0f / 96.0f);
      float var  = sq * (1.0f / 96.0f) - mean * mean;
      st[wv][0] = mean; st[wv][1] = rsqrtf(var + 1e-5f);
    }
  }
  __syncthreads();
  {
    int pp = t / 96, c = t % 96;
    hb2[pp][c] = (hb2[pp][c] - st[pp][0]) * st[pp][1] * g[c] + bb[c];
  }
  __syncthreads();
  float a0 = 0.f, a1 = 0.f, a2 = 0.f, a3 = 0.f;
  #pragma unroll 8
  for (int c = 0; c < 96; c++){
    float w = wti[(long)c * 384 + t];
    a0 += hb2[0][c] * w; a1 += hb2[1][c] * w;
    a2 += hb2[2][c] * w; a3 += hb2[3][c] * w;
  }
  xz[p0 * 384 + t]           = a0;
  xz[(p0 + 1) * 384 + t]     = a1;
  xz[(p0 + 2) * 384 + t]     = a2;
  xz[(p0 + 3) * 384 + t]     = a3;
}

// ---------- depthwise 3x3 conv + bias + silu -> u_t (B,L,Di) channel-last ----------
__global__ void k_dwconv(const float* __restrict__ xz, const float* __restrict__ cwt,
                         const float* __restrict__ cb, float* __restrict__ u_t){
  int tid = threadIdx.x;               // 0..383  (2 pixels x 192 ch)
  int d = tid % 192, px = tid / 192;
  int l = blockIdx.x * 2 + px;
  int b = blockIdx.y;
  int hh = l >> 6, ww = l & 63;
  float acc = cb[d];
  #pragma unroll
  for (int tap = 0; tap < 9; tap++){
    int dh = tap / 3 - 1, dw = tap % 3 - 1;
    int h2 = hh + dh, w2 = ww + dw;
    if (h2 < 0 || h2 >= 64 || w2 < 0 || w2 >= 64) continue;
    acc += xz[((long)(b * L_ + h2 * 64 + w2)) * 384 + d] * cwt[tap * 192 + d];
  }
  u_t[((long)b * L_ + l) * 192 + d] = siluf(acc);
}

// ---------- x_dbl rows (8 waves, 5 uniform cols/wave, float4 LDS) ----------
__global__ void __launch_bounds__(512) k_xdbl(const float* __restrict__ u_t,
                                              const float* __restrict__ xw,
                                              float* __restrict__ xd2){
  __shared__ __align__(16) float su[64][196];   // stride 196: f4-aligned, conflict-free
  int bk = blockIdx.y; int b = bk >> 2, k = bk & 3;
  int l0 = blockIdx.x * 64;
  int tid = threadIdx.x;               // 0..511
  for (int e = tid; e < 64 * 48; e += 512){
    int r = e / 48, s2 = e - r * 48;
    int idx = dir_idx(k, l0 + r);
    *(float4*)&su[r][s2 * 4] = *(const float4*)&u_t[((long)b * L_ + idx) * 192 + s2 * 4];
  }
  __syncthreads();
  int lane = tid & 63, wv = tid >> 6;  // wv 0..7 wave-uniform
  const float* wb = xw + (long)k * 38 * 192;
  float acc[5] = {0.f, 0.f, 0.f, 0.f, 0.f};
  for (int d = 0; d < 192; d += 4){
    float4 uv = *(const float4*)&su[lane][d];
    #pragma unroll
    for (int j = 0; j < 5; j++){
      int c = 8 * j + wv;
      if (c < 38){
        const float* wp = wb + c * 192 + d;     // wave-uniform -> s_load
        acc[j] += uv.x * wp[0] + uv.y * wp[1] + uv.z * wp[2] + uv.w * wp[3];
      }
    }
  }
  float* rowp = xd2 + ((long)bk * L_ + (l0 + lane)) * RW_;
  #pragma unroll
  for (int j = 0; j < 5; j++){
    int c = 8 * j + wv;
    if (c < 38){
      int pos = (c < 6) ? 32 + c : c - 6;  // dt -> 32..37, B -> 0..15, C -> 16..31
      rowp[pos] = acc[j];
    }
  }
}

// ================= chunked selective scan =================
// Lane = channel d (192 threads = 3 waves per block); each lane owns all 16
// states in registers. xd2 row address is wave-uniform -> scalar loads.
// dA = exp2(dlt*Av'), Av' = -exp(A_log)*log2(e). Chunk product of dA collapses
// to exp2(Av' * sum(dlt)).

__global__ void __launch_bounds__(192) k_scan1(
    const float* __restrict__ xd2, const float* __restrict__ Alog,
    const float* __restrict__ dtw, const float* __restrict__ dtb,
    const float* __restrict__ u_t,
    float* __restrict__ P, float* __restrict__ S){
  int bid = blockIdx.x;
  int chunk = bid & (CH_ - 1); int bk = bid >> 6;
  int k = bk & 3, b = bk >> 2;
  int d = threadIdx.x;
  int kd = k * 192 + d;
  float Av[16];
  #pragma unroll
  for (int n = 0; n < 16; n++) Av[n] = -__expf(Alog[kd * 16 + n]) * 1.44269504089f;
  float w0 = dtw[kd*6+0], w1 = dtw[kd*6+1], w2 = dtw[kd*6+2];
  float w3 = dtw[kd*6+3], w4 = dtw[kd*6+4], w5 = dtw[kd*6+5];
  float bias = dtb[kd];
  const float* xrow = xd2 + (long)(b * K_ + k) * L_ * RW_;
  const float* ub = u_t + (long)b * L_ * 192 + d;
  float h[16];
  #pragma unroll
  for (int n = 0; n < 16; n++) h[n] = 0.f;
  float sdlt = 0.f;
  int l0 = chunk * CL_;
  #pragma unroll 2
  for (int l = l0; l < l0 + CL_; l++){
    const float* rp = xrow + (long)l * RW_;   // wave-uniform
    float bv[16];
    #pragma unroll
    for (int n = 0; n < 16; n++) bv[n] = rp[n];
    float r0 = rp[32], r1 = rp[33], r2 = rp[34], r3 = rp[35], r4 = rp[36], r5 = rp[37];
    float dlt = softplus_fast(bias + w0*r0 + w1*r1 + w2*r2 + w3*r3 + w4*r4 + w5*r5);
    float uv = ub[(long)dir_idx(k, l) * 192];
    float du = dlt * uv;
    sdlt += dlt;
    #pragma unroll
    for (int n = 0; n < 16; n++){
      float a = exp2f(dlt * Av[n]);
      h[n] = a * h[n] + du * bv[n];
    }
  }
  long t = (long)(bk * 192 + d) * 16;
  float* Pp = P + (long)chunk * TL_ + t;
  float* Sp = S + (long)chunk * TL_ + t;
  #pragma unroll
  for (int n = 0; n < 16; n += 4){
    *(float4*)&Pp[n] = make_float4(exp2f(Av[n]*sdlt),   exp2f(Av[n+1]*sdlt),
                                   exp2f(Av[n+2]*sdlt), exp2f(Av[n+3]*sdlt));
    *(float4*)&Sp[n] = make_float4(h[n], h[n+1], h[n+2], h[n+3]);
  }
}

// serial scan over chunks; writes Hin IN-PLACE over S
__global__ void k_scan2(const float* __restrict__ P, float* __restrict__ S){
  int t = blockIdx.x * 256 + threadIdx.x;      // 0..TL_-1
  float h = 0.f;
  for (int c = 0; c < CH_; c++){
    float p = P[(long)c * TL_ + t];
    float s = S[(long)c * TL_ + t];
    S[(long)c * TL_ + t] = h;                  // Hin for chunk c
    h = p * h + s;
  }
}

__global__ void __launch_bounds__(192) k_scan3(
    const float* __restrict__ xd2, const float* __restrict__ Alog,
    const float* __restrict__ dtw, const float* __restrict__ dtb,
    const float* __restrict__ Dsk, const float* __restrict__ u_t,
    const float* __restrict__ Hin, float* __restrict__ ycl){
  int bid = blockIdx.x;
  int chunk = bid & (CH_ - 1); int bk = bid >> 6;
  int k = bk & 3, b = bk >> 2;
  int d = threadIdx.x;
  int kd = k * 192 + d;
  float Av[16];
  #pragma unroll
  for (int n = 0; n < 16; n++) Av[n] = -__expf(Alog[kd * 16 + n]) * 1.44269504089f;
  float w0 = dtw[kd*6+0], w1 = dtw[kd*6+1], w2 = dtw[kd*6+2];
  float w3 = dtw[kd*6+3], w4 = dtw[kd*6+4], w5 = dtw[kd*6+5];
  float bias = dtb[kd];
  float Dv = Dsk[kd];
  const float* xrow = xd2 + (long)(b * K_ + k) * L_ * RW_;
  const float* ub = u_t + (long)b * L_ * 192 + d;
  float* yb = ycl + (long)b * L_ * 192;
  long t = (long)(bk * 192 + d) * 16;
  float h[16];
  const float* Hp = Hin + (long)chunk * TL_ + t;
  #pragma unroll
  for (int n = 0; n < 16; n += 4){
    float4 hv = *(const float4*)&Hp[n];
    h[n] = hv.x; h[n+1] = hv.y; h[n+2] = hv.z; h[n+3] = hv.w;
  }
  int l0 = chunk * CL_;
  #pragma unroll 2
  for (int l = l0; l < l0 + CL_; l++){
    const float* rp = xrow + (long)l * RW_;   // wave-uniform
    float bv[16], cv[16];
    #pragma unroll
    for (int n = 0; n < 16; n++){ bv[n] = rp[n]; cv[n] = rp[16 + n]; }
    float r0 = rp[32], r1 = rp[33], r2 = rp[34], r3 = rp[35], r4 = rp[36], r5 = rp[37];
    float dlt = softplus_fast(bias + w0*r0 + w1*r1 + w2*r2 + w3*r3 + w4*r4 + w5*r5);
    int idx = dir_idx(k, l);
    float uv = ub[(long)idx * 192];
    float du = dlt * uv;
    float pr = Dv * uv;
    #pragma unroll
    for (int n = 0; n < 16; n++){
      float a = exp2f(dlt * Av[n]);
      h[n] = a * h[n] + du * bv[n];
      pr += h[n] * cv[n];
    }
    atomicAdd(&yb[(long)idx * 192 + d], pr);
  }
}

// ---------- fused out_norm (LN 192) * silu(z) + out_proj + skip1 ----------
__global__ void __launch_bounds__(384) k_outfuse(const float* __restrict__ ycl,
                                                const float* __restrict__ xz,
                                                const float* __restrict__ g,
                                                const float* __restrict__ bb,
                                                const float* __restrict__ wt,
                                                const float* __restrict__ xf,
                                                const float* __restrict__ skip,
                                                float* __restrict__ xc){
  __shared__ float yb[2][192];
  __shared__ float red[6][2];
  __shared__ float st[2][2];
  long p0 = (long)blockIdx.x * 2;
  int t = threadIdx.x;                 // 0..383
  int pp = t / 192, e = t % 192;
  int wv = t >> 6;                     // 0..5 (waves 0-2 -> pp0, 3-5 -> pp1)
  long p = p0 + pp;
  float v = ycl[p * 192 + e];
  float s  = wave_sum(v);
  float sq = wave_sum(v * v);
  if ((t & 63) == 0){ red[wv][0] = s; red[wv][1] = sq; }
  __syncthreads();
  if (t < 2){
    float ss = red[t*3][0] + red[t*3+1][0] + red[t*3+2][0];
    float qq = red[t*3][1] + red[t*3+1][1] + red[t*3+2][1];
    float mean = ss * (1.0f / 192.0f);
    float var  = qq * (1.0f / 192.0f) - mean * mean;
    st[t][0] = mean; st[t][1] = rsqrtf(var + 1e-5f);
  }
  __syncthreads();
  float zz = xz[p * 384 + 192 + e];
  yb[pp][e] = ((v - st[pp][0]) * st[pp][1] * g[e] + bb[e]) * siluf(zz);
  __syncthreads();
  if (t < 192){
    int pp2 = t / 96, c = t % 96;
    float acc = 0.f;
    #pragma unroll 8
    for (int d = 0; d < 192; d++) acc += yb[pp2][d] * wt[d * 96 + c];
    long pq = p0 + pp2;
    xc[pq * 96 + c] = xf[pq * 96 + c] * skip[c] + acc;
  }
}

// ---------- CAB conv1 3x3 96->32 + exact gelu (weights [tap][ci][o]) ----------
__global__ void k_cab1(const float* __restrict__ in, const float* __restrict__ w1t,
                       const float* __restrict__ b1, float* __restrict__ t1){
  int t = threadIdx.x;
  int o = t & 31, pl = t >> 5;
  long pix = (long)blockIdx.x * 8 + pl;
  int b = (int)(pix >> 12); int l = (int)(pix & 4095);
  int hh = l >> 6, ww = l & 63;
  float acc = b1[o];
  for (int dh = -1; dh <= 1; dh++){
    int h2 = hh + dh; if (h2 < 0 || h2 >= 64) continue;
    for (int dw = -1; dw <= 1; dw++){
      int w2 = ww + dw; if (w2 < 0 || w2 >= 64) continue;
      const float* ir = in + ((long)b * L_ + h2 * 64 + w2) * 96;
      const float* wr = w1t + (long)((dh + 1) * 3 + (dw + 1)) * 96 * 32 + o;
      #pragma unroll
      for (int ci = 0; ci < 96; ci += 4){
        float4 iv = *(const float4*)&ir[ci];
        acc += iv.x * wr[ci*32] + iv.y * wr[(ci+1)*32]
             + iv.z * wr[(ci+2)*32] + iv.w * wr[(ci+3)*32];
      }
    }
  }
  t1[pix * 32 + o] = 0.5f * acc * (1.0f + erff(acc * 0.70710678118654752f));
}

// ---------- CAB conv2 3x3 32->96 (weights [tap][ci][o]) ----------
__global__ void k_cab2(const float* __restrict__ t1, const float* __restrict__ w2t,
                       const float* __restrict__ b2, float* __restrict__ yc){
  int t = threadIdx.x;
  int o = t % 96, pl = t / 96;
  long pix = (long)blockIdx.x * 2 + pl;
  int b = (int)(pix >> 12); int l = (int)(pix & 4095);
  int hh = l >> 6, ww = l & 63;
  float acc = b2[o];
  for (int dh = -1; dh <= 1; dh++){
    int h2 = hh + dh; if (h2 < 0 || h2 >= 64) continue;
    for (int dw = -1; dw <= 1; dw++){
      int w2i = ww + dw; if (w2i < 0 || w2i >= 64) continue;
      const float* ir = t1 + ((long)b * L_ + h2 * 64 + w2i) * 32;
      const float* wr = w2t + (long)((dh + 1) * 3 + (dw + 1)) * 32 * 96 + o;
      #pragma unroll
      for (int ci = 0; ci < 32; ci += 4){
        float4 iv = *(const float4*)&ir[ci];
        acc += iv.x * wr[ci*96] + iv.y * wr[(ci+1)*96]
             + iv.z * wr[(ci+2)*96] + iv.w * wr[(ci+3)*96];
      }
    }
  }
  yc[pix * 96 + o] = acc;
}

// ---------- channel-attention ----------
__global__ void k_meanpart(const float* __restrict__ yc, float* __restrict__ part){
  int b = blockIdx.x >> 5, ch = blockIdx.x & 31;
  int o = threadIdx.x;
  float acc = 0.f;
  const float* base = yc + ((long)b * L_ + ch * 128) * 96 + o;
  for (int r = 0; r < 128; r++) acc += base[(long)r * 96];
  part[(long)blockIdx.x * 96 + o] = acc;
}
__global__ void k_attn(const float* __restrict__ part, const float* __restrict__ dw,
                       const float* __restrict__ db, const float* __restrict__ uw,
                       const float* __restrict__ ub, float* __restrict__ a){
  __shared__ float pv[96];
  __shared__ float tv[3];
  int b = blockIdx.x, o = threadIdx.x;
  float acc = 0.f;
  for (int ch = 0; ch < 32; ch++) acc += part[(long)(b * 32 + ch) * 96 + o];
  pv[o] = acc * (1.0f / 4096.0f);
  __syncthreads();
  if (o < 3){
    float t = db[o];
    for (int i2 = 0; i2 < 96; i2++) t += pv[i2] * dw[o * 96 + i2];
    tv[o] = t > 0.f ? t : 0.f;
  }
  __syncthreads();
  float av = ub[o] + tv[0] * uw[o * 3 + 0] + tv[1] * uw[o * 3 + 1] + tv[2] * uw[o * 3 + 2];
  a[b * 96 + o] = 1.0f / (1.0f + __expf(-av));
}

// ---------- final mix ----------
__global__ void k_mix(const float* __restrict__ xc, const float* __restrict__ yc,
                      const float* __restrict__ a, const float* __restrict__ skip2,
                      float* __restrict__ xf){
  long i = (long)blockIdx.x * 256 + threadIdx.x;
  int c = (int)(i % 96); long p = i / 96; int b = (int)(p >> 12);
  xf[i] = xc[i] * skip2[c] + yc[i] * a[b * 96 + c];
}

extern "C" void kernel_launch(void* const* d_in, const int* in_sizes, int n_in,
                              void* d_out, int out_size, void* d_ws, size_t ws_size,
                              hipStream_t stream){
  const float* x          = (const float*)d_in[0];
  const float* ln1_g      = (const float*)d_in[1];
  const float* ln1_b      = (const float*)d_in[2];
  const float* in_proj_w  = (const float*)d_in[3];
  const float* conv_w     = (const float*)d_in[4];
  const float* conv_b     = (const float*)d_in[5];
  const float* x_proj_w   = (const float*)d_in[6];
  const float* dt_proj_w  = (const float*)d_in[7];
  const float* dt_proj_b  = (const float*)d_in[8];
  const float* A_logs     = (const float*)d_in[9];
  const float* Ds         = (const float*)d_in[10];
  const float* out_norm_g = (const float*)d_in[11];
  const float* out_norm_b = (const float*)d_in[12];
  const float* out_proj_w = (const float*)d_in[13];
  const float* skip1      = (const float*)d_in[14];
  const float* ln2_g      = (const float*)d_in[15];
  const float* ln2_b      = (const float*)d_in[16];
  const float* cab1_w     = (const float*)d_in[17];
  const float* cab1_b     = (const float*)d_in[18];
  const float* cab2_w     = (const float*)d_in[19];
  const float* cab2_b     = (const float*)d_in[20];
  const float* ca_dw      = (const float*)d_in[21];
  const float* ca_db      = (const float*)d_in[22];
  const float* ca_uw      = (const float*)d_in[23];
  const float* ca_ub      = (const float*)d_in[24];
  const float* skip2      = (const float*)d_in[25];

  float* W = (float*)d_ws;
  float* xf   = W + 0;         // 786432   (B,L,C)
  float* hb   = W + 786432;    // 786432   ln2 out
  float* xz   = W + 1572864;   // 3145728  (B,L,384)
  float* u_t  = W + 4718592;   // 1572864  (B,L,Di) conv+silu, channel-last
  float* xd2  = W + 6291456;   // 1310720  (B,K,L,RW_)
  float* ycl  = W + 7602176;   // 1572864  (B,L,Di)  [P overlay during scan]
  float* xc   = W + 9175040;   // 786432   [S/Hin overlay lower half]
  float* ycab = W + 9961472;   // 786432   [S/Hin overlay upper half]
  float* wti2 = W + 10747904;  // 2x36864
  float* wto2 = W + 10821632;  // 2x18432
  float* wt12 = W + 10858496;  // 2x27648
  float* wt22 = W + 10913792;  // 2x27648
  float* cwt2 = W + 10969088;  // 2x1728   -> end 10972544 (43.9 MB)
  // aliases into u_t's region (dead during CAB phase):
  float* t1   = u_t;                 // 262144 (B,L,32)
  float* part = u_t + 262144;        // 6144
  float* abuf = u_t + 268288;        // 192
  // scan chunk-state overlays (CH_*TL_ = 1572864 each):
  //   P -> ycl (consumed by scan2; ycl memset AFTER scan2)
  //   S -> xc..ycab contiguous; Hin written in-place over S by scan2
  float* P   = ycl;
  float* S   = xc;

  k_nchw2nhwc<<<dim3(3072), dim3(256), 0, stream>>>(x, xf);
  k_prep<<<dim3((2*PSZ_ + 255)/256), dim3(256), 0, stream>>>(
      in_proj_w, out_proj_w, cab1_w, cab2_w, conv_w, wti2, wto2, wt12, wt22, cwt2);

  for (int i = 0; i < 2; i++){
    const float* xpw  = x_proj_w   + (long)i * 4 * 38 * 192;
    const float* dtw  = dt_proj_w  + (long)i * 4 * 192 * 6;
    const float* dtbp = dt_proj_b  + (long)i * 4 * 192;
    const float* alog = A_logs     + (long)i * 768 * 16;
    const float* dsp  = Ds         + (long)i * 768;
    const float* wti = wti2 + i * 36864;
    const float* wto = wto2 + i * 18432;
    const float* wt1 = wt12 + i * 27648;
    const float* wt2 = wt22 + i * 27648;
    const float* cwt = cwt2 + i * 1728;

    k_infuse<<<dim3(2048), dim3(384), 0, stream>>>(xf, wti, ln1_g + i*96, ln1_b + i*96, xz);
    k_dwconv<<<dim3(2048, 2), dim3(384), 0, stream>>>(xz, cwt, conv_b + i*192, u_t);
    k_xdbl<<<dim3(64, 8), dim3(512), 0, stream>>>(u_t, xpw, xd2);

    // chunked scan: pass1 -> (P,S), pass2 -> Hin (in-place), memset y, pass3 -> y
    k_scan1<<<dim3(512), dim3(192), 0, stream>>>(xd2, alog, dtw, dtbp, u_t, P, S);
    k_scan2<<<dim3(96), dim3(256), 0, stream>>>(P, S);
    hipMemsetAsync(ycl, 0, (size_t)1572864 * sizeof(float), stream);
    k_scan3<<<dim3(512), dim3(192), 0, stream>>>(xd2, alog, dtw, dtbp, dsp, u_t, S, ycl);

    k_outfuse<<<dim3(4096), dim3(384), 0, stream>>>(ycl, xz, out_norm_g + i*192,
                                                    out_norm_b + i*192, wto, xf,
                                                    skip1 + i*96, xc);

    k_ln96<<<dim3(2048), dim3(256), 0, stream>>>(xc, hb, ln2_g + i*96, ln2_b + i*96);
    k_cab1<<<dim3(1024), dim3(256), 0, stream>>>(hb, wt1, cab1_b + i*32, t1);
    k_cab2<<<dim3(4096), dim3(192), 0, stream>>>(t1, wt2, cab2_b + i*96, ycab);
    k_meanpart<<<dim3(64), dim3(96), 0, stream>>>(ycab, part);
    k_attn<<<dim3(2), dim3(96), 0, stream>>>(part, ca_dw + i*288, ca_db + i*3,
                                             ca_uw + i*288, ca_ub + i*96, abuf);
    k_mix<<<dim3(3072), dim3(256), 0, stream>>>(xc, ycab, abuf, skip2 + i*96, xf);
  }

  k_nhwc2nchw<<<dim3(3072), dim3(256), 0, stream>>>(xf, (float*)d_out);
}

// Round 7
// 758.702 us; speedup vs baseline: 10.5312x; 1.0152x over previous
//
#include <hip/hip_runtime.h>
#include <math.h>

// Problem constants (fixed by the reference)
constexpr int B_  = 2;
constexpr int L_  = 4096;   // H*W
constexpr int Di_ = 192;    // D_INNER
constexpr int K_  = 4;      // directions
constexpr int CH_ = 64;     // scan chunks
constexpr int CL_ = 64;     // chunk length (CH_*CL_ == L_)
constexpr int TL_ = 24576;  // total state lanes = B*K*Di*N
constexpr int RW_ = 40;     // xd row stride: [B(16) | C(16) | dt(6) | pad(2)]
constexpr int PSZ_ = 112320; // per-layer prepped-weight floats

__device__ __forceinline__ float siluf(float x){ return x / (1.0f + __expf(-x)); }
__device__ __forceinline__ float softplus_fast(float x){
  return x > 15.0f ? x : __logf(1.0f + __expf(x));
}
__device__ __forceinline__ float wave_sum(float v){
  #pragma unroll
  for (int off = 32; off > 0; off >>= 1) v += __shfl_xor(v, off, 64);
  return v;
}
// direction index maps: scan position l -> row-major spatial index
__device__ __forceinline__ int dir_idx(int k, int l){
  if (k == 0) return l;
  if (k == 1) return ((l & 63) << 6) | (l >> 6);
  if (k == 2) return (L_ - 1) - l;
  int lm = (L_ - 1) - l; return ((lm & 63) << 6) | (lm >> 6);
}

// ---------- layout shufflers ----------
__global__ void k_nchw2nhwc(const float* __restrict__ x, float* __restrict__ xf){
  long i = (long)blockIdx.x * 256 + threadIdx.x;
  int c = (int)(i % 96); long p = i / 96; int b = (int)(p >> 12); int l = (int)(p & 4095);
  xf[i] = x[((long)b * 96 + c) * L_ + l];
}
__global__ void k_nhwc2nchw(const float* __restrict__ xf, float* __restrict__ out){
  long i = (long)blockIdx.x * 256 + threadIdx.x;
  int l = (int)(i & 4095); long q = i >> 12; int c = (int)(q % 96); int b = (int)(q / 96);
  out[i] = xf[((long)b * L_ + l) * 96 + c];
}

// ---------- single prep kernel: all weight transforms, both layers ----------
__global__ void k_prep(const float* __restrict__ ipw, const float* __restrict__ opw,
                       const float* __restrict__ c1w, const float* __restrict__ c2w,
                       const float* __restrict__ cw,
                       float* __restrict__ wti, float* __restrict__ wto,
                       float* __restrict__ wt1, float* __restrict__ wt2,
                       float* __restrict__ cwt){
  int t = blockIdx.x * 256 + threadIdx.x;
  if (t >= 2 * PSZ_) return;
  int i = t / PSZ_, r = t % PSZ_;
  if (r < 36864){
    int rr = r / 96, c = r % 96;
    wti[i*36864 + c*384 + rr] = ipw[(long)i*36864 + r];
  } else if ((r -= 36864) < 18432){
    int c = r / 192, d = r % 192;
    wto[i*18432 + d*96 + c] = opw[(long)i*18432 + r];
  } else if ((r -= 18432) < 27648){
    int tap = r % 9; int rem = r / 9; int ci = rem % 96; int o = rem / 96;
    wt1[i*27648 + (tap*96+ci)*32 + o] = c1w[(long)i*27648 + r];
  } else if ((r -= 27648) < 27648){
    int tap = r % 9; int rem = r / 9; int ci = rem % 32; int o = rem / 32;
    wt2[i*27648 + (tap*32+ci)*96 + o] = c2w[(long)i*27648 + r];
  } else {
    r -= 27648;
    int d = r / 9, tap = r % 9;
    cwt[i*1728 + tap*192 + d] = cw[(long)i*1728 + r];
  }
}

// ---------- layernorm over 96 channels (wave per pixel) ----------
__global__ void k_ln96(const float* __restrict__ in, float* __restrict__ out,
                       const float* __restrict__ g, const float* __restrict__ bb){
  int wave = threadIdx.x >> 6, lane = threadIdx.x & 63;
  long p = (long)blockIdx.x * 4 + wave;
  const float* row = in + p * 96;
  float v0 = row[lane];
  float v1 = (lane < 32) ? row[64 + lane] : 0.0f;
  float s  = wave_sum(v0 + v1);
  float sq = wave_sum(v0 * v0 + v1 * v1);
  float mean = s * (1.0f / 96.0f);
  float var  = sq * (1.0f / 96.0f) - mean * mean;
  float rs = rsqrtf(var + 1e-5f);
  out[p * 96 + lane] = (v0 - mean) * rs * g[lane] + bb[lane];
  if (lane < 32) out[p * 96 + 64 + lane] = (v1 - mean) * rs * g[64 + lane] + bb[64 + lane];
}

// ---------- fused LN1 + in_proj, 4 pixels per block ----------
__global__ void __launch_bounds__(384) k_infuse(const float* __restrict__ xf,
                                               const float* __restrict__ wti,
                                               const float* __restrict__ g,
                                               const float* __restrict__ bb,
                                               float* __restrict__ xz){
  __shared__ float hb2[4][96];
  __shared__ float st[4][2];
  long p0 = (long)blockIdx.x * 4;
  int t = threadIdx.x;                 // 0..383
  {
    int pp = t / 96, c = t % 96;
    hb2[pp][c] = xf[(p0 + pp) * 96 + c];
  }
  __syncthreads();
  int wv = t >> 6, lane = t & 63;
  if (wv < 4){
    float v0 = hb2[wv][lane];
    float v1 = (lane < 32) ? hb2[wv][64 + lane] : 0.0f;
    float s  = wave_sum(v0 + v1);
    float sq = wave_sum(v0 * v0 + v1 * v1);
    if (lane == 0){
      float mean = s * (1.0f / 96.0f);
      float var  = sq * (1.0f / 96.0f) - mean * mean;
      st[wv][0] = mean; st[wv][1] = rsqrtf(var + 1e-5f);
    }
  }
  __syncthreads();
  {
    int pp = t / 96, c = t % 96;
    hb2[pp][c] = (hb2[pp][c] - st[pp][0]) * st[pp][1] * g[c] + bb[c];
  }
  __syncthreads();
  float a0 = 0.f, a1 = 0.f, a2 = 0.f, a3 = 0.f;
  #pragma unroll 8
  for (int c = 0; c < 96; c++){
    float w = wti[(long)c * 384 + t];
    a0 += hb2[0][c] * w; a1 += hb2[1][c] * w;
    a2 += hb2[2][c] * w; a3 += hb2[3][c] * w;
  }
  xz[p0 * 384 + t]           = a0;
  xz[(p0 + 1) * 384 + t]     = a1;
  xz[(p0 + 2) * 384 + t]     = a2;
  xz[(p0 + 3) * 384 + t]     = a3;
}

// ---------- depthwise 3x3 conv + bias + silu -> u_t (B,L,Di) channel-last ----------
__global__ void k_dwconv(const float* __restrict__ xz, const float* __restrict__ cwt,
                         const float* __restrict__ cb, float* __restrict__ u_t){
  int tid = threadIdx.x;               // 0..383  (2 pixels x 192 ch)
  int d = tid % 192, px = tid / 192;
  int l = blockIdx.x * 2 + px;
  int b = blockIdx.y;
  int hh = l >> 6, ww = l & 63;
  float acc = cb[d];
  #pragma unroll
  for (int tap = 0; tap < 9; tap++){
    int dh = tap / 3 - 1, dw = tap % 3 - 1;
    int h2 = hh + dh, w2 = ww + dw;
    if (h2 < 0 || h2 >= 64 || w2 < 0 || w2 >= 64) continue;
    acc += xz[((long)(b * L_ + h2 * 64 + w2)) * 384 + d] * cwt[tap * 192 + d];
  }
  u_t[((long)b * L_ + l) * 192 + d] = siluf(acc);
}

// ---------- x_dbl rows (8 waves, 5 uniform cols/wave, float4 LDS) ----------
__global__ void __launch_bounds__(512) k_xdbl(const float* __restrict__ u_t,
                                              const float* __restrict__ xw,
                                              float* __restrict__ xd2){
  __shared__ __align__(16) float su[64][196];   // stride 196: f4-aligned, conflict-free
  int bk = blockIdx.y; int b = bk >> 2, k = bk & 3;
  int l0 = blockIdx.x * 64;
  int tid = threadIdx.x;               // 0..511
  for (int e = tid; e < 64 * 48; e += 512){
    int r = e / 48, s2 = e - r * 48;
    int idx = dir_idx(k, l0 + r);
    *(float4*)&su[r][s2 * 4] = *(const float4*)&u_t[((long)b * L_ + idx) * 192 + s2 * 4];
  }
  __syncthreads();
  int lane = tid & 63, wv = tid >> 6;  // wv 0..7 wave-uniform
  const float* wb = xw + (long)k * 38 * 192;
  float acc[5] = {0.f, 0.f, 0.f, 0.f, 0.f};
  for (int d = 0; d < 192; d += 4){
    float4 uv = *(const float4*)&su[lane][d];
    #pragma unroll
    for (int j = 0; j < 5; j++){
      int c = 8 * j + wv;
      if (c < 38){
        const float* wp = wb + c * 192 + d;     // wave-uniform -> s_load
        acc[j] += uv.x * wp[0] + uv.y * wp[1] + uv.z * wp[2] + uv.w * wp[3];
      }
    }
  }
  float* rowp = xd2 + ((long)bk * L_ + (l0 + lane)) * RW_;
  #pragma unroll
  for (int j = 0; j < 5; j++){
    int c = 8 * j + wv;
    if (c < 38){
      int pos = (c < 6) ? 32 + c : c - 6;  // dt -> 32..37, B -> 0..15, C -> 16..31
      rowp[pos] = acc[j];
    }
  }
}

// ================= chunked selective scan =================
__global__ void __launch_bounds__(192) k_scan1(
    const float* __restrict__ xd2, const float* __restrict__ Alog,
    const float* __restrict__ dtw, const float* __restrict__ dtb,
    const float* __restrict__ u_t,
    float* __restrict__ P, float* __restrict__ S){
  int bid = blockIdx.x;
  int chunk = bid & (CH_ - 1); int bk = bid >> 6;
  int k = bk & 3, b = bk >> 2;
  int d = threadIdx.x;
  int kd = k * 192 + d;
  float Av[16];
  #pragma unroll
  for (int n = 0; n < 16; n++) Av[n] = -__expf(Alog[kd * 16 + n]) * 1.44269504089f;
  float w0 = dtw[kd*6+0], w1 = dtw[kd*6+1], w2 = dtw[kd*6+2];
  float w3 = dtw[kd*6+3], w4 = dtw[kd*6+4], w5 = dtw[kd*6+5];
  float bias = dtb[kd];
  const float* xrow = xd2 + (long)(b * K_ + k) * L_ * RW_;
  const float* ub = u_t + (long)b * L_ * 192 + d;
  float h[16];
  #pragma unroll
  for (int n = 0; n < 16; n++) h[n] = 0.f;
  float sdlt = 0.f;
  int l0 = chunk * CL_;
  #pragma unroll 2
  for (int l = l0; l < l0 + CL_; l++){
    const float* rp = xrow + (long)l * RW_;   // wave-uniform
    float bv[16];
    #pragma unroll
    for (int n = 0; n < 16; n++) bv[n] = rp[n];
    float r0 = rp[32], r1 = rp[33], r2 = rp[34], r3 = rp[35], r4 = rp[36], r5 = rp[37];
    float dlt = softplus_fast(bias + w0*r0 + w1*r1 + w2*r2 + w3*r3 + w4*r4 + w5*r5);
    float uv = ub[(long)dir_idx(k, l) * 192];
    float du = dlt * uv;
    sdlt += dlt;
    #pragma unroll
    for (int n = 0; n < 16; n++){
      float a = exp2f(dlt * Av[n]);
      h[n] = a * h[n] + du * bv[n];
    }
  }
  long t = (long)(bk * 192 + d) * 16;
  float* Pp = P + (long)chunk * TL_ + t;
  float* Sp = S + (long)chunk * TL_ + t;
  #pragma unroll
  for (int n = 0; n < 16; n += 4){
    *(float4*)&Pp[n] = make_float4(exp2f(Av[n]*sdlt),   exp2f(Av[n+1]*sdlt),
                                   exp2f(Av[n+2]*sdlt), exp2f(Av[n+3]*sdlt));
    *(float4*)&Sp[n] = make_float4(h[n], h[n+1], h[n+2], h[n+3]);
  }
}

// serial scan over chunks; writes Hin IN-PLACE over S
__global__ void k_scan2(const float* __restrict__ P, float* __restrict__ S){
  int t = blockIdx.x * 256 + threadIdx.x;      // 0..TL_-1
  float h = 0.f;
  for (int c = 0; c < CH_; c++){
    float p = P[(long)c * TL_ + t];
    float s = S[(long)c * TL_ + t];
    S[(long)c * TL_ + t] = h;                  // Hin for chunk c
    h = p * h + s;
  }
}

__global__ void __launch_bounds__(192) k_scan3(
    const float* __restrict__ xd2, const float* __restrict__ Alog,
    const float* __restrict__ dtw, const float* __restrict__ dtb,
    const float* __restrict__ Dsk, const float* __restrict__ u_t,
    const float* __restrict__ Hin, float* __restrict__ ycl){
  int bid = blockIdx.x;
  int chunk = bid & (CH_ - 1); int bk = bid >> 6;
  int k = bk & 3, b = bk >> 2;
  int d = threadIdx.x;
  int kd = k * 192 + d;
  float Av[16];
  #pragma unroll
  for (int n = 0; n < 16; n++) Av[n] = -__expf(Alog[kd * 16 + n]) * 1.44269504089f;
  float w0 = dtw[kd*6+0], w1 = dtw[kd*6+1], w2 = dtw[kd*6+2];
  float w3 = dtw[kd*6+3], w4 = dtw[kd*6+4], w5 = dtw[kd*6+5];
  float bias = dtb[kd];
  float Dv = Dsk[kd];
  const float* xrow = xd2 + (long)(b * K_ + k) * L_ * RW_;
  const float* ub = u_t + (long)b * L_ * 192 + d;
  float* yb = ycl + (long)b * L_ * 192;
  long t = (long)(bk * 192 + d) * 16;
  float h[16];
  const float* Hp = Hin + (long)chunk * TL_ + t;
  #pragma unroll
  for (int n = 0; n < 16; n += 4){
    float4 hv = *(const float4*)&Hp[n];
    h[n] = hv.x; h[n+1] = hv.y; h[n+2] = hv.z; h[n+3] = hv.w;
  }
  int l0 = chunk * CL_;
  #pragma unroll 2
  for (int l = l0; l < l0 + CL_; l++){
    const float* rp = xrow + (long)l * RW_;   // wave-uniform
    float bv[16], cv[16];
    #pragma unroll
    for (int n = 0; n < 16; n++){ bv[n] = rp[n]; cv[n] = rp[16 + n]; }
    float r0 = rp[32], r1 = rp[33], r2 = rp[34], r3 = rp[35], r4 = rp[36], r5 = rp[37];
    float dlt = softplus_fast(bias + w0*r0 + w1*r1 + w2*r2 + w3*r3 + w4*r4 + w5*r5);
    int idx = dir_idx(k, l);
    float uv = ub[(long)idx * 192];
    float du = dlt * uv;
    float pr = Dv * uv;
    #pragma unroll
    for (int n = 0; n < 16; n++){
      float a = exp2f(dlt * Av[n]);
      h[n] = a * h[n] + du * bv[n];
      pr += h[n] * cv[n];
    }
    atomicAdd(&yb[(long)idx * 192 + d], pr);
  }
}

// ---------- fused out_norm (LN 192) * silu(z) + out_proj + skip1 ----------
__global__ void __launch_bounds__(384) k_outfuse(const float* __restrict__ ycl,
                                                const float* __restrict__ xz,
                                                const float* __restrict__ g,
                                                const float* __restrict__ bb,
                                                const float* __restrict__ wt,
                                                const float* __restrict__ xf,
                                                const float* __restrict__ skip,
                                                float* __restrict__ xc){
  __shared__ float yb[2][192];
  __shared__ float red[6][2];
  __shared__ float st[2][2];
  long p0 = (long)blockIdx.x * 2;
  int t = threadIdx.x;                 // 0..383
  int pp = t / 192, e = t % 192;
  int wv = t >> 6;                     // 0..5 (waves 0-2 -> pp0, 3-5 -> pp1)
  long p = p0 + pp;
  float v = ycl[p * 192 + e];
  float s  = wave_sum(v);
  float sq = wave_sum(v * v);
  if ((t & 63) == 0){ red[wv][0] = s; red[wv][1] = sq; }
  __syncthreads();
  if (t < 2){
    float ss = red[t*3][0] + red[t*3+1][0] + red[t*3+2][0];
    float qq = red[t*3][1] + red[t*3+1][1] + red[t*3+2][1];
    float mean = ss * (1.0f / 192.0f);
    float var  = qq * (1.0f / 192.0f) - mean * mean;
    st[t][0] = mean; st[t][1] = rsqrtf(var + 1e-5f);
  }
  __syncthreads();
  float zz = xz[p * 384 + 192 + e];
  yb[pp][e] = ((v - st[pp][0]) * st[pp][1] * g[e] + bb[e]) * siluf(zz);
  __syncthreads();
  if (t < 192){
    int pp2 = t / 96, c = t % 96;
    float acc = 0.f;
    #pragma unroll 8
    for (int d = 0; d < 192; d++) acc += yb[pp2][d] * wt[d * 96 + c];
    long pq = p0 + pp2;
    xc[pq * 96 + c] = xf[pq * 96 + c] * skip[c] + acc;
  }
}

// ---------- CAB conv1 3x3 96->32 + gelu, LDS-tiled 4x4 pixels ----------
// block: 128 threads = 32 o x 4 quarters; each thread computes 4 pixels.
__global__ void __launch_bounds__(128) k_cab1(const float* __restrict__ in,
                                              const float* __restrict__ w1t,
                                              const float* __restrict__ b1,
                                              float* __restrict__ t1){
  __shared__ __align__(16) float su[36 * 96];   // 6x6 halo x 96 ch = 13.8 KB
  int blk = blockIdx.x;                // 512 = B * 256 tiles
  int b = blk >> 8; int tile = blk & 255;
  int th0 = (tile >> 4) * 4, tw0 = (tile & 15) * 4;
  int tid = threadIdx.x;
  for (int e = tid; e < 36 * 24; e += 128){
    int pos = e / 24, c4 = e % 24;
    int r = pos / 6, c = pos % 6;
    int h2 = th0 + r - 1, w2 = tw0 + c - 1;
    float4 v = make_float4(0.f, 0.f, 0.f, 0.f);
    if (h2 >= 0 && h2 < 64 && w2 >= 0 && w2 < 64)
      v = *(const float4*)&in[((long)b * L_ + h2 * 64 + w2) * 96 + c4 * 4];
    *(float4*)&su[pos * 96 + c4 * 4] = v;
  }
  __syncthreads();
  int o = tid & 31, q = tid >> 5;      // q 0..3 -> pixels q*4..q*4+3
  float bv = b1[o];
  float acc[4] = {bv, bv, bv, bv};
  int pr[4], pc[4];
  #pragma unroll
  for (int j = 0; j < 4; j++){ int px = q * 4 + j; pr[j] = px >> 2; pc[j] = px & 3; }
  for (int tap = 0; tap < 9; tap++){
    int dh = tap / 3, dw = tap % 3;    // offset into 6x6 halo
    const float* wb = w1t + (long)tap * 96 * 32 + o;
    for (int ci = 0; ci < 96; ci += 4){
      float wv0 = wb[ci * 32], wv1 = wb[(ci+1) * 32];
      float wv2 = wb[(ci+2) * 32], wv3 = wb[(ci+3) * 32];
      #pragma unroll
      for (int j = 0; j < 4; j++){
        float4 iv = *(const float4*)&su[((pr[j] + dh) * 6 + (pc[j] + dw)) * 96 + ci];
        acc[j] += iv.x * wv0 + iv.y * wv1 + iv.z * wv2 + iv.w * wv3;
      }
    }
  }
  #pragma unroll
  for (int j = 0; j < 4; j++){
    float a = acc[j];
    float gel = 0.5f * a * (1.0f + erff(a * 0.70710678118654752f));
    t1[((long)b * L_ + (th0 + pr[j]) * 64 + (tw0 + pc[j])) * 32 + o] = gel;
  }
}

// ---------- CAB conv2 3x3 32->96, LDS-tiled 4x4 pixels ----------
// block: 192 threads = 96 o x 2 halves; each thread computes 8 pixels.
__global__ void __launch_bounds__(192) k_cab2(const float* __restrict__ t1,
                                              const float* __restrict__ w2t,
                                              const float* __restrict__ b2,
                                              float* __restrict__ yc){
  __shared__ __align__(16) float su[36 * 32];   // 6x6 halo x 32 ch = 4.6 KB
  int blk = blockIdx.x;                // 512 = B * 256 tiles
  int b = blk >> 8; int tile = blk & 255;
  int th0 = (tile >> 4) * 4, tw0 = (tile & 15) * 4;
  int tid = threadIdx.x;
  for (int e = tid; e < 36 * 8; e += 192){
    int pos = e / 8, c4 = e % 8;
    int r = pos / 6, c = pos % 6;
    int h2 = th0 + r - 1, w2 = tw0 + c - 1;
    float4 v = make_float4(0.f, 0.f, 0.f, 0.f);
    if (h2 >= 0 && h2 < 64 && w2 >= 0 && w2 < 64)
      v = *(const float4*)&t1[((long)b * L_ + h2 * 64 + w2) * 32 + c4 * 4];
    *(float4*)&su[pos * 32 + c4 * 4] = v;
  }
  __syncthreads();
  int o = tid % 96, half = tid / 96;   // half 0..1 -> pixels half*8..half*8+7
  float bv = b2[o];
  float acc[8] = {bv, bv, bv, bv, bv, bv, bv, bv};
  int pr[8], pc[8];
  #pragma unroll
  for (int j = 0; j < 8; j++){ int px = half * 8 + j; pr[j] = px >> 2; pc[j] = px & 3; }
  for (int tap = 0; tap < 9; tap++){
    int dh = tap / 3, dw = tap % 3;
    const float* wb = w2t + (long)tap * 32 * 96 + o;
    for (int ci = 0; ci < 32; ci += 4){
      float wv0 = wb[ci * 96], wv1 = wb[(ci+1) * 96];
      float wv2 = wb[(ci+2) * 96], wv3 = wb[(ci+3) * 96];
      #pragma unroll
      for (int j = 0; j < 8; j++){
        float4 iv = *(const float4*)&su[((pr[j] + dh) * 6 + (pc[j] + dw)) * 32 + ci];
        acc[j] += iv.x * wv0 + iv.y * wv1 + iv.z * wv2 + iv.w * wv3;
      }
    }
  }
  #pragma unroll
  for (int j = 0; j < 8; j++)
    yc[((long)b * L_ + (th0 + pr[j]) * 64 + (tw0 + pc[j])) * 96 + o] = acc[j];
}

// ---------- channel-attention ----------
__global__ void k_meanpart(const float* __restrict__ yc, float* __restrict__ part){
  int b = blockIdx.x >> 5, ch = blockIdx.x & 31;
  int o = threadIdx.x;
  float acc = 0.f;
  const float* base = yc + ((long)b * L_ + ch * 128) * 96 + o;
  for (int r = 0; r < 128; r++) acc += base[(long)r * 96];
  part[(long)blockIdx.x * 96 + o] = acc;
}
__global__ void k_attn(const float* __restrict__ part, const float* __restrict__ dw,
                       const float* __restrict__ db, const float* __restrict__ uw,
                       const float* __restrict__ ub, float* __restrict__ a){
  __shared__ float pv[96];
  __shared__ float tv[3];
  int b = blockIdx.x, o = threadIdx.x;
  float acc = 0.f;
  for (int ch = 0; ch < 32; ch++) acc += part[(long)(b * 32 + ch) * 96 + o];
  pv[o] = acc * (1.0f / 4096.0f);
  __syncthreads();
  if (o < 3){
    float t = db[o];
    for (int i2 = 0; i2 < 96; i2++) t += pv[i2] * dw[o * 96 + i2];
    tv[o] = t > 0.f ? t : 0.f;
  }
  __syncthreads();
  float av = ub[o] + tv[0] * uw[o * 3 + 0] + tv[1] * uw[o * 3 + 1] + tv[2] * uw[o * 3 + 2];
  a[b * 96 + o] = 1.0f / (1.0f + __expf(-av));
}

// ---------- final mix ----------
__global__ void k_mix(const float* __restrict__ xc, const float* __restrict__ yc,
                      const float* __restrict__ a, const float* __restrict__ skip2,
                      float* __restrict__ xf){
  long i = (long)blockIdx.x * 256 + threadIdx.x;
  int c = (int)(i % 96); long p = i / 96; int b = (int)(p >> 12);
  xf[i] = xc[i] * skip2[c] + yc[i] * a[b * 96 + c];
}

extern "C" void kernel_launch(void* const* d_in, const int* in_sizes, int n_in,
                              void* d_out, int out_size, void* d_ws, size_t ws_size,
                              hipStream_t stream){
  const float* x          = (const float*)d_in[0];
  const float* ln1_g      = (const float*)d_in[1];
  const float* ln1_b      = (const float*)d_in[2];
  const float* in_proj_w  = (const float*)d_in[3];
  const float* conv_w     = (const float*)d_in[4];
  const float* conv_b     = (const float*)d_in[5];
  const float* x_proj_w   = (const float*)d_in[6];
  const float* dt_proj_w  = (const float*)d_in[7];
  const float* dt_proj_b  = (const float*)d_in[8];
  const float* A_logs     = (const float*)d_in[9];
  const float* Ds         = (const float*)d_in[10];
  const float* out_norm_g = (const float*)d_in[11];
  const float* out_norm_b = (const float*)d_in[12];
  const float* out_proj_w = (const float*)d_in[13];
  const float* skip1      = (const float*)d_in[14];
  const float* ln2_g      = (const float*)d_in[15];
  const float* ln2_b      = (const float*)d_in[16];
  const float* cab1_w     = (const float*)d_in[17];
  const float* cab1_b     = (const float*)d_in[18];
  const float* cab2_w     = (const float*)d_in[19];
  const float* cab2_b     = (const float*)d_in[20];
  const float* ca_dw      = (const float*)d_in[21];
  const float* ca_db      = (const float*)d_in[22];
  const float* ca_uw      = (const float*)d_in[23];
  const float* ca_ub      = (const float*)d_in[24];
  const float* skip2      = (const float*)d_in[25];

  float* W = (float*)d_ws;
  float* xf   = W + 0;         // 786432   (B,L,C)
  float* hb   = W + 786432;    // 786432   ln2 out
  float* xz   = W + 1572864;   // 3145728  (B,L,384)
  float* u_t  = W + 4718592;   // 1572864  (B,L,Di) conv+silu, channel-last
  float* xd2  = W + 6291456;   // 1310720  (B,K,L,RW_)
  float* ycl  = W + 7602176;   // 1572864  (B,L,Di)  [P overlay during scan]
  float* xc   = W + 9175040;   // 786432   [S/Hin overlay lower half]
  float* ycab = W + 9961472;   // 786432   [S/Hin overlay upper half]
  float* wti2 = W + 10747904;  // 2x36864
  float* wto2 = W + 10821632;  // 2x18432
  float* wt12 = W + 10858496;  // 2x27648
  float* wt22 = W + 10913792;  // 2x27648
  float* cwt2 = W + 10969088;  // 2x1728   -> end 10972544 (43.9 MB)
  // aliases into u_t's region (dead during CAB phase):
  float* t1   = u_t;                 // 262144 (B,L,32)
  float* part = u_t + 262144;        // 6144
  float* abuf = u_t + 268288;        // 192
  // scan chunk-state overlays (CH_*TL_ = 1572864 each):
  float* P   = ycl;
  float* S   = xc;

  k_nchw2nhwc<<<dim3(3072), dim3(256), 0, stream>>>(x, xf);
  k_prep<<<dim3((2*PSZ_ + 255)/256), dim3(256), 0, stream>>>(
      in_proj_w, out_proj_w, cab1_w, cab2_w, conv_w, wti2, wto2, wt12, wt22, cwt2);

  for (int i = 0; i < 2; i++){
    const float* xpw  = x_proj_w   + (long)i * 4 * 38 * 192;
    const float* dtw  = dt_proj_w  + (long)i * 4 * 192 * 6;
    const float* dtbp = dt_proj_b  + (long)i * 4 * 192;
    const float* alog = A_logs     + (long)i * 768 * 16;
    const float* dsp  = Ds         + (long)i * 768;
    const float* wti = wti2 + i * 36864;
    const float* wto = wto2 + i * 18432;
    const float* wt1 = wt12 + i * 27648;
    const float* wt2 = wt22 + i * 27648;
    const float* cwt = cwt2 + i * 1728;

    k_infuse<<<dim3(2048), dim3(384), 0, stream>>>(xf, wti, ln1_g + i*96, ln1_b + i*96, xz);
    k_dwconv<<<dim3(2048, 2), dim3(384), 0, stream>>>(xz, cwt, conv_b + i*192, u_t);
    k_xdbl<<<dim3(64, 8), dim3(512), 0, stream>>>(u_t, xpw, xd2);

    // chunked scan: pass1 -> (P,S), pass2 -> Hin (in-place), memset y, pass3 -> y
    k_scan1<<<dim3(512), dim3(192), 0, stream>>>(xd2, alog, dtw, dtbp, u_t, P, S);
    k_scan2<<<dim3(96), dim3(256), 0, stream>>>(P, S);
    hipMemsetAsync(ycl, 0, (size_t)1572864 * sizeof(float), stream);
    k_scan3<<<dim3(512), dim3(192), 0, stream>>>(xd2, alog, dtw, dtbp, dsp, u_t, S, ycl);

    k_outfuse<<<dim3(4096), dim3(384), 0, stream>>>(ycl, xz, out_norm_g + i*192,
                                                    out_norm_b + i*192, wto, xf,
                                                    skip1 + i*96, xc);

    k_ln96<<<dim3(2048), dim3(256), 0, stream>>>(xc, hb, ln2_g + i*96, ln2_b + i*96);
    k_cab1<<<dim3(512), dim3(128), 0, stream>>>(hb, wt1, cab1_b + i*32, t1);
    k_cab2<<<dim3(512), dim3(192), 0, stream>>>(t1, wt2, cab2_b + i*96, ycab);
    k_meanpart<<<dim3(64), dim3(96), 0, stream>>>(ycab, part);
    k_attn<<<dim3(2), dim3(96), 0, stream>>>(part, ca_dw + i*288, ca_db + i*3,
                                             ca_uw + i*288, ca_ub + i*96, abuf);
    k_mix<<<dim3(3072), dim3(256), 0, stream>>>(xc, ycab, abuf, skip2 + i*96, xf);
  }

  k_nhwc2nchw<<<dim3(3072), dim3(256), 0, stream>>>(xf, (float*)d_out);
}